// Round 7
// baseline (180.289 us; speedup 1.0000x reference)
//
#include <hip/hip_runtime.h>
#include <hip/hip_cooperative_groups.h>
#include <math.h>

#define D 128
#define DEG 64           // per-node slot capacity (mean degree 32)
#define BK 128           // dst buckets per direction (64 nodes/bucket)
#define CH 256           // edge chunks per direction (1024 edges/chunk)
#define CAP 32           // slots per (bucket,chunk) cell; mean 8, P(>32)~1e-13

typedef __attribute__((ext_vector_type(8))) short bf8;
typedef __attribute__((ext_vector_type(4))) float f4;

__device__ __forceinline__ unsigned hash_u32(unsigned x){
  x ^= x >> 16; x *= 0x7feb352du; x ^= x >> 15; x *= 0x846ca68bu; x ^= x >> 16;
  return x;
}
__device__ __forceinline__ unsigned f2bfbits(float f){
  unsigned u = __float_as_uint(f);
  return (u + 0x7fffu + ((u >> 16) & 1u)) >> 16;   // RNE bf16
}
__device__ __forceinline__ float bflo(unsigned u){ return __uint_as_float(u << 16); }
__device__ __forceinline__ float bfhi(unsigned u){ return __uint_as_float(u & 0xffff0000u); }
__device__ __forceinline__ uint4 pack8(float4 v0, float4 v1){
  uint4 o;
  o.x = f2bfbits(v0.x) | (f2bfbits(v0.y) << 16);
  o.y = f2bfbits(v0.z) | (f2bfbits(v0.w) << 16);
  o.z = f2bfbits(v1.x) | (f2bfbits(v1.y) << 16);
  o.w = f2bfbits(v1.z) | (f2bfbits(v1.w) << 16);
  return o;
}
// XCD-aware type partition (perf heuristic; bijective, correctness-neutral).
__device__ __forceinline__ int xcd_remap(int bid, int jobs_per_type){
  if (jobs_per_type & 3) return bid;
  const int xcd = bid & 7, slot = bid >> 3;
  const int q = jobs_per_type >> 2;
  return (xcd >> 2) * jobs_per_type + (xcd & 3) * q + slot;
}

struct LinS  { alignas(16) ushort Ws[64 * 128]; alignas(16) ushort As[4][16 * 128]; }; // 32KB
struct BinS  { int hist[BK]; int ex[BK]; int cur[BK]; unsigned buf[1024]; };           // 5.5KB
struct LossS { alignas(16) ushort A[16 * 128]; float lpos[16]; float2 part[4][16];
               int list[16 * DEG]; int lcnt[16]; unsigned cc[CH]; };                   // ~10KB
union SharedU { LinS lin; BinS bin; LossS loss; };                                     // 32KB

// ---- stage A part 1: linear ctx0 = bf16(x @ W^T + b), emits x16 -----------
__device__ __forceinline__
void stage_linear(SharedU& sh, int bid,
                  const float* __restrict__ xa, const float* __restrict__ xb,
                  const float* __restrict__ Wa, const float* __restrict__ Wb,
                  const float* __restrict__ ba, const float* __restrict__ bb,
                  ushort* __restrict__ x16a, ushort* __restrict__ x16b,
                  ushort* __restrict__ oa, ushort* __restrict__ ob, int N){
  const int nb64 = N >> 6;
  const int jid = xcd_remap(bid, nb64);
  const int type = jid >= nb64;
  const int r0 = (jid - (type ? nb64 : 0)) << 6;
  const float* __restrict__ x = type ? xb : xa;
  const float* __restrict__ W = type ? Wb : Wa;
  const float* __restrict__ bias = type ? bb : ba;
  ushort* __restrict__ x16 = type ? x16b : x16a;
  ushort* __restrict__ out = type ? ob : oa;
  const int t = threadIdx.x, w = t >> 6, l = t & 63;

  #define STAGE_W(H)                                                        \
  {                                                                         \
    _Pragma("unroll")                                                       \
    for (int i = 0; i < 4; i++){                                            \
      const int cid = i * 256 + t;                                          \
      const int col = cid >> 4, kq = cid & 15;                              \
      const int gcol = (H) * 64 + col;                                      \
      const float4 v0 = *(const float4*)(W + (gcol << 7) + (kq << 3));      \
      const float4 v1 = *(const float4*)(W + (gcol << 7) + (kq << 3) + 4);  \
      *(uint4*)&sh.lin.Ws[(col << 7) + ((kq ^ (col & 7)) << 3)] = pack8(v0, v1); \
    }                                                                       \
  }

  #pragma unroll
  for (int i = 0; i < 4; i++){
    const int cid = i * 64 + l;
    const int row = cid >> 4, kq = cid & 15;
    const size_t gr = (size_t)(r0 + w * 16 + row);
    const float4 v0 = *(const float4*)(x + (gr << 7) + (kq << 3));
    const float4 v1 = *(const float4*)(x + (gr << 7) + (kq << 3) + 4);
    const uint4 o = pack8(v0, v1);
    *(uint4*)&sh.lin.As[w][(row << 7) + ((kq ^ (row & 7)) << 3)] = o;
    *(uint4*)(x16 + (gr << 7) + (kq << 3)) = o;
  }
  STAGE_W(0)
  __syncthreads();

  const int rloc = l & 15, kg = l >> 4;
  bf8 af[4];
  #pragma unroll
  for (int ks = 0; ks < 4; ks++){
    const int kq = ks * 4 + kg;
    af[ks] = *(const bf8*)&sh.lin.As[w][(rloc << 7) + ((kq ^ (rloc & 7)) << 3)];
  }
  #pragma unroll
  for (int h = 0; h < 2; h++){
    if (h == 1){
      __syncthreads();
      STAGE_W(1)
      __syncthreads();
    }
    #pragma unroll
    for (int c2 = 0; c2 < 4; c2++){
      const int ct = h * 4 + c2;
      f4 acc = {0.f, 0.f, 0.f, 0.f};
      const int col = ct * 16 + rloc;
      const int lcol = c2 * 16 + rloc;          // (col&7)==(lcol&7)
      #pragma unroll
      for (int ks = 0; ks < 4; ks++){
        const int kq = ks * 4 + kg;
        const bf8 bfr = *(const bf8*)&sh.lin.Ws[(lcol << 7) + ((kq ^ (lcol & 7)) << 3)];
        acc = __builtin_amdgcn_mfma_f32_16x16x32_bf16(af[ks], bfr, acc, 0, 0, 0);
      }
      const float bv = bias[col];
      #pragma unroll
      for (int r = 0; r < 4; r++){
        const int row = r0 + w * 16 + kg * 4 + r;
        out[((size_t)row << 7) + col] = (ushort)f2bfbits(acc[r] + bv);
      }
    }
  }
  #undef STAGE_W
}

// ---- stage A part 2: fixed-slot binning (no global atomics) ---------------
// Each (bucket,chunk) cell is owned by exactly ONE block -> no cross-block
// coordination, no gcnt, no prep zeroing. ccnt written unconditionally.
__device__ __forceinline__
void stage_bin(SharedU& sh, int sbid,
               const int* __restrict__ e_ba, const int* __restrict__ e_ab,
               unsigned* __restrict__ scratch, unsigned* __restrict__ ccnt, int E){
  const int d = sbid >> 8, chunk = sbid & 255;
  const int* __restrict__ e = d ? e_ab : e_ba;
  const int t = threadIdx.x;
  if (t < BK) sh.bin.hist[t] = 0;
  __syncthreads();

  int ds[4], ss[4];
  const int base = chunk * 1024;
  #pragma unroll
  for (int k = 0; k < 4; k++){
    const int i = base + k * 256 + t;
    const bool ok = i < E;
    ds[k] = ok ? e[E + i] : -1;
    ss[k] = ok ? e[i] : 0;
    if (ok) atomicAdd(&sh.bin.hist[ds[k] >> 6], 1);
  }
  __syncthreads();
  if (t < BK) sh.bin.ex[t] = sh.bin.hist[t];
  __syncthreads();
  for (int off = 1; off < BK; off <<= 1){
    int v = 0;
    if (t < BK && t >= off) v = sh.bin.ex[t - off];
    __syncthreads();
    if (t < BK) sh.bin.ex[t] += v;
    __syncthreads();
  }
  if (t < BK){ sh.bin.ex[t] -= sh.bin.hist[t]; sh.bin.cur[t] = sh.bin.ex[t]; }
  __syncthreads();
  #pragma unroll
  for (int k = 0; k < 4; k++){
    if (ds[k] >= 0){
      const int p = atomicAdd(&sh.bin.cur[ds[k] >> 6], 1);
      sh.bin.buf[p] = (unsigned)ss[k] | ((unsigned)ds[k] << 13);
    }
  }
  __syncthreads();
  int nv = E - base; nv = nv < 0 ? 0 : (nv > 1024 ? 1024 : nv);
  if (t < BK) ccnt[(size_t)(d * BK + t) * CH + chunk] = (unsigned)min(sh.bin.hist[t], CAP);
  for (int s = t; s < nv; s += 256){
    const unsigned v = sh.bin.buf[s];
    const int bkt = (int)(v >> 19);
    const int gp = s - sh.bin.ex[bkt];
    if (gp < CAP) scratch[((size_t)(d * BK + bkt) * CH + chunk) * CAP + gp] = v;
  }
}

// ---- stage B: bucket-scan + gather-mean + contrastive loss ----------------
__device__ __forceinline__
void stage_loss(SharedU& sh,
                const ushort* __restrict__ xa, const ushort* __restrict__ xb,
                const ushort* __restrict__ ctx0a, const ushort* __restrict__ ctx0b,
                const unsigned* __restrict__ scratch, const unsigned* __restrict__ ccnt,
                float* __restrict__ out, int n){
  const int nb = n >> 4;
  const int jid = xcd_remap((int)blockIdx.x, nb);
  const int type = jid >= nb;
  const int r0 = (jid - (type ? nb : 0)) << 4;
  const ushort* __restrict__ x    = type ? xb : xa;
  const ushort* __restrict__ feat = type ? ctx0a : ctx0b;
  const int t = threadIdx.x, w = t >> 6, l = t & 63;
  const int sg = l >> 4, q = l & 15;
  auto& L = sh.loss;

  const unsigned h = hash_u32((unsigned)jid * 2654435761u + 0x9E3779B9u);
  const unsigned bo = h & 8191u;
  const unsigned aa = (((h >> 13) & 4095u) << 1) | 1u;

  if (t < 16) L.lcnt[t] = 0;
  const int bkt = r0 >> 6;
  const size_t cellbase = (size_t)(type * BK + bkt) * CH;
  if (t < CH) L.cc[t] = ccnt[cellbase + t];
  __syncthreads();

  { // phase 0: scan owned bucket cells (contiguous, count-masked)
    for (int i = t; i < CH * CAP; i += 256){
      const int cell = i >> 5, slot = i & (CAP - 1);
      if (slot < (int)L.cc[cell]){
        const unsigned v = scratch[cellbase * CAP + i];
        const int dl = (int)((v >> 13) & 8191u) - r0;
        if ((unsigned)dl < 16u){
          const int p = atomicAdd(&L.lcnt[dl], 1);
          if (p < DEG) L.list[dl * DEG + p] = (int)(v & 8191u);
        }
      }
    }
  }
  __syncthreads();

  { // phase 1: gather-mean for node row = w*4+sg
    const int row = w * 4 + sg;
    const int c = min(L.lcnt[row], DEG);
    const int lb2 = row * DEG;
    int sl0 = L.list[lb2 + q];
    int sl1 = L.list[lb2 + 16 + q];
    int sl2 = L.list[lb2 + 32 + q];
    int sl3 = L.list[lb2 + 48 + q];

    float a0=0.f,a1=0.f,a2=0.f,a3=0.f,a4=0.f,a5=0.f,a6=0.f,a7=0.f;
    const int lbase = l & 48;
    #define GMEAN_CHUNK(SL, J)                                                 \
    if (c > (J)*16){                                                           \
      _Pragma("unroll")                                                        \
      for (int i = 0; i < 16; i++){                                            \
        const int raw = __shfl((SL), lbase | i, 64);                           \
        const bool ok = (J)*16 + i < c;                                        \
        const int src = ok ? raw : 0;                                          \
        const float wt = ok ? 1.0f : 0.0f;                                     \
        const uint4 v = *(const uint4*)(feat + ((size_t)src << 7) + (q << 3)); \
        a0 += wt*bflo(v.x); a1 += wt*bfhi(v.x); a2 += wt*bflo(v.y); a3 += wt*bfhi(v.y); \
        a4 += wt*bflo(v.z); a5 += wt*bfhi(v.z); a6 += wt*bflo(v.w); a7 += wt*bfhi(v.w); \
      }                                                                        \
    }
    GMEAN_CHUNK(sl0, 0) GMEAN_CHUNK(sl1, 1) GMEAN_CHUNK(sl2, 2) GMEAN_CHUNK(sl3, 3)
    #undef GMEAN_CHUNK

    const float inv = 1.0f / (float)(c > 1 ? c : 1);
    uint4 o;
    o.x = f2bfbits(a0*inv) | (f2bfbits(a1*inv) << 16);
    o.y = f2bfbits(a2*inv) | (f2bfbits(a3*inv) << 16);
    o.z = f2bfbits(a4*inv) | (f2bfbits(a5*inv) << 16);
    o.w = f2bfbits(a6*inv) | (f2bfbits(a7*inv) << 16);
    *(uint4*)&L.A[(row << 7) + ((q ^ (row & 7)) << 3)] = o;
  }
  __syncthreads();

  // phase 2: MFMA tiles with direct-global B, online LSE
  const int nloc = l & 15, kg = l >> 4;
  bf8 af[4];
  #pragma unroll
  for (int ks = 0; ks < 4; ks++){
    const int kq = ks * 4 + kg;
    af[ks] = *(const bf8*)&L.A[(nloc << 7) + ((kq ^ (nloc & 7)) << 3)];
  }

  float M0=-1e30f, M1=-1e30f, M2=-1e30f, M3=-1e30f;
  float S0=0.f, S1=0.f, S2=0.f, S3=0.f;

  for (int tile = w; tile < 17; tile += 4){
    const int colid = tile * 16 + nloc;
    const int jn = colid - 16;
    const bool isneg = colid >= 16;
    const int g = isneg ? (int)((aa * (unsigned)jn + bo) & 8191u) : (r0 + colid);

    const ushort* __restrict__ xr = x + ((size_t)g << 7);
    f4 acc = {0.f, 0.f, 0.f, 0.f};
    #pragma unroll
    for (int ks = 0; ks < 4; ks++){
      const bf8 bfr = *(const bf8*)(xr + ks * 32 + kg * 8);
      acc = __builtin_amdgcn_mfma_f32_16x16x32_bf16(af[ks], bfr, acc, 0, 0, 0);
    }
    #pragma unroll
    for (int r = 0; r < 4; r++){
      const int row = kg * 4 + r;
      const bool valid = isneg ? (jn < 255 && g != r0 + row) : (colid == row);
      const float v = acc[r] * 10.0f;
      if (!isneg && colid == row) L.lpos[row] = v;
      float* Mp; float* Sp;
      if (r == 0){ Mp = &M0; Sp = &S0; } else if (r == 1){ Mp = &M1; Sp = &S1; }
      else if (r == 2){ Mp = &M2; Sp = &S2; } else { Mp = &M3; Sp = &S3; }
      if (valid){
        const float Mn = fmaxf(*Mp, v);
        *Sp = *Sp * __expf(*Mp - Mn) + __expf(v - Mn);
        *Mp = Mn;
      }
    }
  }

  #define MERGE_LANES(MV, SV)                          \
  {                                                    \
    _Pragma("unroll")                                  \
    for (int o = 1; o < 16; o <<= 1){                  \
      const float Mo = __shfl_xor((MV), o);            \
      const float So = __shfl_xor((SV), o);            \
      const float Mn = fmaxf((MV), Mo);                \
      (SV) = (SV) * __expf((MV) - Mn) + So * __expf(Mo - Mn); \
      (MV) = Mn;                                       \
    }                                                  \
  }
  MERGE_LANES(M0, S0) MERGE_LANES(M1, S1) MERGE_LANES(M2, S2) MERGE_LANES(M3, S3)
  #undef MERGE_LANES

  if (nloc == 0){
    L.part[w][kg * 4 + 0] = make_float2(M0, S0);
    L.part[w][kg * 4 + 1] = make_float2(M1, S1);
    L.part[w][kg * 4 + 2] = make_float2(M2, S2);
    L.part[w][kg * 4 + 3] = make_float2(M3, S3);
  }
  __syncthreads();

  if (w == 0 && l < 16){
    const int row = l;
    float Mm = -1e30f, Ss = 0.f;
    #pragma unroll
    for (int j = 0; j < 4; j++){
      const float2 ps = L.part[j][row];
      const float Mn = fmaxf(Mm, ps.x);
      Ss = Ss * __expf(Mm - Mn) + ps.y * __expf(ps.x - Mn);
      Mm = Mn;
    }
    float term = Mm + __logf(Ss) - L.lpos[row];
    #pragma unroll
    for (int o = 8; o >= 1; o >>= 1) term += __shfl_xor(term, o);
    if (l == 0) atomicAdd(out, term / (logf(256.0f) * (float)(2 * n)));
  }
}

#define FUSED_PARAMS                                                          \
    const float* __restrict__ xa, const float* __restrict__ xb,               \
    const float* __restrict__ Wa, const float* __restrict__ Wb,               \
    const float* __restrict__ ba, const float* __restrict__ bb,               \
    const int* __restrict__ e_ba, const int* __restrict__ e_ab,               \
    ushort* __restrict__ x16a, ushort* __restrict__ x16b,                     \
    ushort* __restrict__ oa, ushort* __restrict__ ob,                         \
    unsigned* __restrict__ scratch, unsigned* __restrict__ ccnt,              \
    float* __restrict__ out, int E, int N

__device__ __forceinline__
void stageA_dispatch(SharedU& sh, FUSED_PARAMS){
  const int bid = (int)blockIdx.x;
  const int LB = 2 * (N >> 6);                  // 256
  if (bid < LB){
    stage_linear(sh, bid, xa, xb, Wa, Wb, ba, bb, x16a, x16b, oa, ob, N);
  } else if (bid < LB + 2 * CH){                // 512 binning blocks
    stage_bin(sh, bid - LB, e_ba, e_ab, scratch, ccnt, E);
  } else if (bid == LB + 2 * CH && threadIdx.x == 0){
    *out = 0.0f;
  }
}

// ---- single cooperative kernel: stage A -> grid.sync -> stage B -----------
__global__ __launch_bounds__(256, 4)
void fused_all(FUSED_PARAMS){
  __shared__ SharedU sh;
  stageA_dispatch(sh, xa, xb, Wa, Wb, ba, bb, e_ba, e_ab,
                  x16a, x16b, oa, ob, scratch, ccnt, out, E, N);
  cooperative_groups::this_grid().sync();
  stage_loss(sh, x16a, x16b, oa, ob, scratch, ccnt, out, N);
}

// ---- fallback pair (normal launches) if cooperative launch is rejected ----
__global__ __launch_bounds__(256, 4)
void kA(FUSED_PARAMS){
  __shared__ SharedU sh;
  stageA_dispatch(sh, xa, xb, Wa, Wb, ba, bb, e_ba, e_ab,
                  x16a, x16b, oa, ob, scratch, ccnt, out, E, N);
}
__global__ __launch_bounds__(256, 4)
void kB(FUSED_PARAMS){
  __shared__ SharedU sh;
  stage_loss(sh, x16a, x16b, oa, ob, scratch, ccnt, out, N);
}

extern "C" void kernel_launch(void* const* d_in, const int* in_sizes, int n_in,
                              void* d_out, int out_size, void* d_ws, size_t ws_size,
                              hipStream_t stream) {
  const float* x_a = (const float*)d_in[0];
  const float* x_b = (const float*)d_in[1];
  const float* W_a = (const float*)d_in[2];
  const float* b_a = (const float*)d_in[3];
  const float* W_b = (const float*)d_in[4];
  const float* b_b = (const float*)d_in[5];
  const int*   e_ab = (const int*)d_in[6];   // [2,E]: [0]=src(a), [1]=dst(b)
  const int*   e_ba = (const int*)d_in[7];   // [0]=src(b), [1]=dst(a)
  int E = in_sizes[6] / 2;
  int N = in_sizes[0] / D;                   // 8192

  char* p = (char*)d_ws;
  ushort* xa16    = (ushort*)p;   p += (size_t)N * D * 2;
  ushort* xb16    = (ushort*)p;   p += (size_t)N * D * 2;
  ushort* ctx0a   = (ushort*)p;   p += (size_t)N * D * 2;
  ushort* ctx0b   = (ushort*)p;   p += (size_t)N * D * 2;
  unsigned* scratch = (unsigned*)p; p += (size_t)2 * BK * CH * CAP * 4;  // 8MB
  unsigned* ccnt  = (unsigned*)p; p += (size_t)2 * BK * CH * 4;          // 256KB
  float* outp = (float*)d_out;

  void* args[] = { &x_a, &x_b, &W_a, &W_b, &b_a, &b_b, &e_ba, &e_ab,
                   &xa16, &xb16, &ctx0a, &ctx0b, &scratch, &ccnt,
                   &outp, &E, &N };
  hipError_t err = hipLaunchCooperativeKernel((void*)fused_all, dim3(2 * (N / 16)),
                                              dim3(256), args, 0, stream);
  if (err != hipSuccess){
    (void)hipGetLastError();                 // clear; use 2-launch fallback
    kA<<<2 * (N / 64) + 2 * CH + 1, 256, 0, stream>>>(
        x_a, x_b, W_a, W_b, b_a, b_b, e_ba, e_ab,
        xa16, xb16, ctx0a, ctx0b, scratch, ccnt, outp, E, N);
    kB<<<2 * (N / 16), 256, 0, stream>>>(
        x_a, x_b, W_a, W_b, b_a, b_b, e_ba, e_ab,
        xa16, xb16, ctx0a, ctx0b, scratch, ccnt, outp, E, N);
  }
}

// Round 8
// 62.621 us; speedup vs baseline: 2.8790x; 2.8790x over previous
//
#include <hip/hip_runtime.h>
#include <math.h>

#define D 128
#define DEG 64           // per-node slot capacity (mean degree 32)
#define BK 128           // dst buckets per direction (64 nodes/bucket)
#define CH 256           // edge chunks per direction (1024 edges/chunk)
#define CAP 32           // slots per (bucket,chunk) cell; mean 8, P(>32)~1e-13

typedef __attribute__((ext_vector_type(8))) short bf8;
typedef __attribute__((ext_vector_type(4))) float f4;

__device__ __forceinline__ unsigned hash_u32(unsigned x){
  x ^= x >> 16; x *= 0x7feb352du; x ^= x >> 15; x *= 0x846ca68bu; x ^= x >> 16;
  return x;
}
__device__ __forceinline__ unsigned f2bfbits(float f){
  unsigned u = __float_as_uint(f);
  return (u + 0x7fffu + ((u >> 16) & 1u)) >> 16;   // RNE bf16
}
__device__ __forceinline__ float bflo(unsigned u){ return __uint_as_float(u << 16); }
__device__ __forceinline__ float bfhi(unsigned u){ return __uint_as_float(u & 0xffff0000u); }
__device__ __forceinline__ uint4 pack8(float4 v0, float4 v1){
  uint4 o;
  o.x = f2bfbits(v0.x) | (f2bfbits(v0.y) << 16);
  o.y = f2bfbits(v0.z) | (f2bfbits(v0.w) << 16);
  o.z = f2bfbits(v1.x) | (f2bfbits(v1.y) << 16);
  o.w = f2bfbits(v1.z) | (f2bfbits(v1.w) << 16);
  return o;
}
// XCD-aware type partition (perf heuristic; bijective, correctness-neutral).
__device__ __forceinline__ int xcd_remap(int bid, int jobs_per_type){
  if (jobs_per_type & 3) return bid;
  const int xcd = bid & 7, slot = bid >> 3;
  const int q = jobs_per_type >> 2;
  return (xcd >> 2) * jobs_per_type + (xcd & 3) * q + slot;
}

// ---- K1: convert W once (64KB) + zero out. (No gcnt: fixed-slot binning
// needs no zeroed global counters at all.) ----------------------------------
__global__ __launch_bounds__(256)
void prep_kernel(const float* __restrict__ Wa, const float* __restrict__ Wb,
                 ushort* __restrict__ W16a, ushort* __restrict__ W16b,
                 float* __restrict__ out0){
  const int tid = blockIdx.x * 256 + threadIdx.x;
  if (tid < 2 * (D * D / 8)){
    const int ty = tid >= D * D / 8;
    const int k = tid - (ty ? D * D / 8 : 0);
    const float* __restrict__ src = ty ? Wb : Wa;
    ushort* __restrict__ dst = ty ? W16b : W16a;
    const float4 v0 = *(const float4*)(src + k * 8);
    const float4 v1 = *(const float4*)(src + k * 8 + 4);
    *(uint4*)(dst + k * 8) = pack8(v0, v1);
  }
  if (tid == 0) *out0 = 0.0f;
}

// ---- K2: linear (256 blocks) || fixed-slot binning (512 blocks) -----------
// Binning has ZERO global atomics: each (bucket,chunk) cell is owned by
// exactly one block. r6's S1 waited on 256-deep same-word atomicAdd-return
// chains at the LLC (~the missing ~30us); this removes the chain entirely.
__global__ __launch_bounds__(256)
void linear_bin(const float* __restrict__ xa, const float* __restrict__ xb,
                const ushort* __restrict__ W16a, const ushort* __restrict__ W16b,
                const float* __restrict__ ba, const float* __restrict__ bb,
                ushort* __restrict__ x16a, ushort* __restrict__ x16b,
                ushort* __restrict__ oa, ushort* __restrict__ ob,
                const int* __restrict__ e_ba, const int* __restrict__ e_ab,
                unsigned* __restrict__ scratch, unsigned* __restrict__ ccnt,
                int E, int N){
  const int LB = 2 * (N >> 6);                   // 256 linear blocks (LB%8==0)
  __shared__ alignas(16) ushort As[4][16 * 128]; // 16KB, linear branch only

  if ((int)blockIdx.x < LB){
    // ---------------- ctx0 = bf16(x @ W^T + b) via MFMA ----------------
    const int nb64 = N >> 6;
    const int jid = xcd_remap((int)blockIdx.x, nb64);
    const int type = jid >= nb64;
    const int r0 = (jid - (type ? nb64 : 0)) << 6;
    const float* __restrict__ x = type ? xb : xa;
    const ushort* __restrict__ W16 = type ? W16b : W16a;
    const float* __restrict__ bias = type ? bb : ba;
    ushort* __restrict__ x16 = type ? x16b : x16a;
    ushort* __restrict__ out = type ? ob : oa;
    const int t = threadIdx.x, w = t >> 6, l = t & 63;

    #pragma unroll
    for (int i = 0; i < 4; i++){
      const int cid = i * 64 + l;
      const int row = cid >> 4, kq = cid & 15;
      const size_t gr = (size_t)(r0 + w * 16 + row);
      const float4 v0 = *(const float4*)(x + (gr << 7) + (kq << 3));
      const float4 v1 = *(const float4*)(x + (gr << 7) + (kq << 3) + 4);
      const uint4 o = pack8(v0, v1);
      *(uint4*)&As[w][(row << 7) + ((kq ^ (row & 7)) << 3)] = o;
      *(uint4*)(x16 + (gr << 7) + (kq << 3)) = o;  // 1KB/instr coalesced
    }
    __syncthreads();

    const int rloc = l & 15, kg = l >> 4;
    bf8 af[4];
    #pragma unroll
    for (int ks = 0; ks < 4; ks++){
      const int kq = ks * 4 + kg;
      af[ks] = *(const bf8*)&As[w][(rloc << 7) + ((kq ^ (rloc & 7)) << 3)];
    }
    #pragma unroll
    for (int ct = 0; ct < 8; ct++){
      const int col = ct * 16 + rloc;
      const ushort* __restrict__ wr = W16 + ((size_t)col << 7);  // L2/L1-hot 32KB
      f4 acc = {0.f, 0.f, 0.f, 0.f};
      #pragma unroll
      for (int ks = 0; ks < 4; ks++){
        const bf8 bfr = *(const bf8*)(wr + ks * 32 + kg * 8);
        acc = __builtin_amdgcn_mfma_f32_16x16x32_bf16(af[ks], bfr, acc, 0, 0, 0);
      }
      const float bv = bias[col];
      #pragma unroll
      for (int r = 0; r < 4; r++){
        const int row = r0 + w * 16 + kg * 4 + r;
        out[((size_t)row << 7) + col] = (ushort)f2bfbits(acc[r] + bv);
      }
    }
  } else {
    // -------- fixed-slot binning: block owns (dir, chunk) ----------------
    const int sbid = (int)blockIdx.x - LB;       // 0..511
    const int d = sbid >> 8, chunk = sbid & 255;
    const int* __restrict__ e = d ? e_ab : e_ba;
    const int t = threadIdx.x;
    __shared__ int hist[BK], ex[BK], cur[BK];
    __shared__ unsigned buf[1024];
    if (t < BK) hist[t] = 0;
    __syncthreads();

    int ds[4], ss[4];
    const int base = chunk * 1024;
    #pragma unroll
    for (int k = 0; k < 4; k++){
      const int i = base + k * 256 + t;
      const bool ok = i < E;
      ds[k] = ok ? e[E + i] : -1;
      ss[k] = ok ? e[i] : 0;
      if (ok) atomicAdd(&hist[ds[k] >> 6], 1);   // LDS atomic
    }
    __syncthreads();
    if (t < BK) ex[t] = hist[t];
    __syncthreads();
    for (int off = 1; off < BK; off <<= 1){      // Hillis-Steele over 128 bins
      int v = 0;
      if (t < BK && t >= off) v = ex[t - off];
      __syncthreads();
      if (t < BK) ex[t] += v;
      __syncthreads();
    }
    if (t < BK){ ex[t] -= hist[t]; cur[t] = ex[t]; }  // exclusive starts
    __syncthreads();
    #pragma unroll
    for (int k = 0; k < 4; k++){
      if (ds[k] >= 0){
        const int p = atomicAdd(&cur[ds[k] >> 6], 1);            // LDS atomic
        buf[p] = (unsigned)ss[k] | ((unsigned)ds[k] << 13);
      }
    }
    __syncthreads();
    int nv = E - base; nv = nv < 0 ? 0 : (nv > 1024 ? 1024 : nv);
    if (t < BK) ccnt[(size_t)(d * BK + t) * CH + chunk] = (unsigned)min(hist[t], CAP);
    for (int s = t; s < nv; s += 256){
      const unsigned v = buf[s];
      const int bkt = (int)(v >> 19);            // dst>>6
      const int gp = s - ex[bkt];
      if (gp < CAP) scratch[((size_t)(d * BK + bkt) * CH + chunk) * CAP + gp] = v;
    }
  }
}

// ---- K3: masked bucket-scan + gather-mean + contrastive loss --------------
__global__ __launch_bounds__(256)
void loss_fused(const ushort* __restrict__ xa, const ushort* __restrict__ xb,
                const ushort* __restrict__ ctx0a, const ushort* __restrict__ ctx0b,
                const unsigned* __restrict__ scratch, const unsigned* __restrict__ ccnt,
                float* __restrict__ out, int n){
  const int nb = n >> 4;                          // 512 jobs per type
  const int jid = xcd_remap((int)blockIdx.x, nb); // XCDs 0-3: type 0, XCDs 4-7: type 1
  const int type = jid >= nb;
  const int r0 = (jid - (type ? nb : 0)) << 4;
  const ushort* __restrict__ x    = type ? xb : xa;
  const ushort* __restrict__ feat = type ? ctx0a : ctx0b;
  const int t = threadIdx.x, w = t >> 6, l = t & 63;
  const int sg = l >> 4, q = l & 15;

  __shared__ alignas(16) ushort A[16 * 128];
  __shared__ float lpos[16];
  __shared__ float2 part[4][16];
  __shared__ int list[16 * DEG];
  __shared__ int lcnt[16];
  __shared__ unsigned cc[CH];

  const unsigned h = hash_u32((unsigned)jid * 2654435761u + 0x9E3779B9u);
  const unsigned bo = h & 8191u;
  const unsigned aa = (((h >> 13) & 4095u) << 1) | 1u;

  if (t < 16) lcnt[t] = 0;
  const int bkt = r0 >> 6;
  const size_t cellbase = (size_t)(type * BK + bkt) * CH;
  if (t < CH) cc[t] = ccnt[cellbase + t];
  __syncthreads();

  { // phase 0: scan owned bucket cells (contiguous, count-masked)
    for (int i = t; i < CH * CAP; i += 256){
      const int cell = i >> 5, slot = i & (CAP - 1);
      if (slot < (int)cc[cell]){
        const unsigned v = scratch[cellbase * CAP + i];
        const int dl = (int)((v >> 13) & 8191u) - r0;
        if ((unsigned)dl < 16u){
          const int p = atomicAdd(&lcnt[dl], 1);
          if (p < DEG) list[dl * DEG + p] = (int)(v & 8191u);
        }
      }
    }
  }
  __syncthreads();

  { // phase 1: gather-mean for node row = w*4+sg
    const int row = w * 4 + sg;
    const int c = min(lcnt[row], DEG);
    const int lb2 = row * DEG;
    int sl0 = list[lb2 + q];
    int sl1 = list[lb2 + 16 + q];
    int sl2 = list[lb2 + 32 + q];
    int sl3 = list[lb2 + 48 + q];

    float a0=0.f,a1=0.f,a2=0.f,a3=0.f,a4=0.f,a5=0.f,a6=0.f,a7=0.f;
    const int lbase = l & 48;
    #define GMEAN_CHUNK(SL, J)                                                 \
    if (c > (J)*16){                                                           \
      _Pragma("unroll")                                                        \
      for (int i = 0; i < 16; i++){                                            \
        const int raw = __shfl((SL), lbase | i, 64);                           \
        const bool ok = (J)*16 + i < c;                                        \
        const int src = ok ? raw : 0;                                          \
        const float wt = ok ? 1.0f : 0.0f;                                     \
        const uint4 v = *(const uint4*)(feat + ((size_t)src << 7) + (q << 3)); \
        a0 += wt*bflo(v.x); a1 += wt*bfhi(v.x); a2 += wt*bflo(v.y); a3 += wt*bfhi(v.y); \
        a4 += wt*bflo(v.z); a5 += wt*bfhi(v.z); a6 += wt*bflo(v.w); a7 += wt*bfhi(v.w); \
      }                                                                        \
    }
    GMEAN_CHUNK(sl0, 0) GMEAN_CHUNK(sl1, 1) GMEAN_CHUNK(sl2, 2) GMEAN_CHUNK(sl3, 3)
    #undef GMEAN_CHUNK

    const float inv = 1.0f / (float)(c > 1 ? c : 1);
    uint4 o;
    o.x = f2bfbits(a0*inv) | (f2bfbits(a1*inv) << 16);
    o.y = f2bfbits(a2*inv) | (f2bfbits(a3*inv) << 16);
    o.z = f2bfbits(a4*inv) | (f2bfbits(a5*inv) << 16);
    o.w = f2bfbits(a6*inv) | (f2bfbits(a7*inv) << 16);
    *(uint4*)&A[(row << 7) + ((q ^ (row & 7)) << 3)] = o;
  }
  __syncthreads();

  // phase 2: MFMA tiles with direct-global B, online LSE
  const int nloc = l & 15, kg = l >> 4;
  bf8 af[4];
  #pragma unroll
  for (int ks = 0; ks < 4; ks++){
    const int kq = ks * 4 + kg;
    af[ks] = *(const bf8*)&A[(nloc << 7) + ((kq ^ (nloc & 7)) << 3)];
  }

  float M0=-1e30f, M1=-1e30f, M2=-1e30f, M3=-1e30f;
  float S0=0.f, S1=0.f, S2=0.f, S3=0.f;

  for (int tile = w; tile < 17; tile += 4){
    const int colid = tile * 16 + nloc;
    const int jn = colid - 16;
    const bool isneg = colid >= 16;
    const int g = isneg ? (int)((aa * (unsigned)jn + bo) & 8191u) : (r0 + colid);

    const ushort* __restrict__ xr = x + ((size_t)g << 7);
    f4 acc = {0.f, 0.f, 0.f, 0.f};
    #pragma unroll
    for (int ks = 0; ks < 4; ks++){
      const bf8 bfr = *(const bf8*)(xr + ks * 32 + kg * 8);
      acc = __builtin_amdgcn_mfma_f32_16x16x32_bf16(af[ks], bfr, acc, 0, 0, 0);
    }
    #pragma unroll
    for (int r = 0; r < 4; r++){
      const int row = kg * 4 + r;
      const bool valid = isneg ? (jn < 255 && g != r0 + row) : (colid == row);
      const float v = acc[r] * 10.0f;
      if (!isneg && colid == row) lpos[row] = v;
      float* Mp; float* Sp;
      if (r == 0){ Mp = &M0; Sp = &S0; } else if (r == 1){ Mp = &M1; Sp = &S1; }
      else if (r == 2){ Mp = &M2; Sp = &S2; } else { Mp = &M3; Sp = &S3; }
      if (valid){
        const float Mn = fmaxf(*Mp, v);
        *Sp = *Sp * __expf(*Mp - Mn) + __expf(v - Mn);
        *Mp = Mn;
      }
    }
  }

  #define MERGE_LANES(MV, SV)                          \
  {                                                    \
    _Pragma("unroll")                                  \
    for (int o = 1; o < 16; o <<= 1){                  \
      const float Mo = __shfl_xor((MV), o);            \
      const float So = __shfl_xor((SV), o);            \
      const float Mn = fmaxf((MV), Mo);                \
      (SV) = (SV) * __expf((MV) - Mn) + So * __expf(Mo - Mn); \
      (MV) = Mn;                                       \
    }                                                  \
  }
  MERGE_LANES(M0, S0) MERGE_LANES(M1, S1) MERGE_LANES(M2, S2) MERGE_LANES(M3, S3)
  #undef MERGE_LANES

  if (nloc == 0){
    part[w][kg * 4 + 0] = make_float2(M0, S0);
    part[w][kg * 4 + 1] = make_float2(M1, S1);
    part[w][kg * 4 + 2] = make_float2(M2, S2);
    part[w][kg * 4 + 3] = make_float2(M3, S3);
  }
  __syncthreads();

  if (w == 0 && l < 16){
    const int row = l;
    float Mm = -1e30f, Ss = 0.f;
    #pragma unroll
    for (int j = 0; j < 4; j++){
      const float2 ps = part[j][row];
      const float Mn = fmaxf(Mm, ps.x);
      Ss = Ss * __expf(Mm - Mn) + ps.y * __expf(ps.x - Mn);
      Mm = Mn;
    }
    float term = Mm + __logf(Ss) - lpos[row];
    #pragma unroll
    for (int o = 8; o >= 1; o >>= 1) term += __shfl_xor(term, o);
    if (l == 0) atomicAdd(out, term / (logf(256.0f) * (float)(2 * n)));
  }
}

extern "C" void kernel_launch(void* const* d_in, const int* in_sizes, int n_in,
                              void* d_out, int out_size, void* d_ws, size_t ws_size,
                              hipStream_t stream) {
  const float* x_a = (const float*)d_in[0];
  const float* x_b = (const float*)d_in[1];
  const float* W_a = (const float*)d_in[2];
  const float* b_a = (const float*)d_in[3];
  const float* W_b = (const float*)d_in[4];
  const float* b_b = (const float*)d_in[5];
  const int*   e_ab = (const int*)d_in[6];   // [2,E]: [0]=src(a), [1]=dst(b)
  const int*   e_ba = (const int*)d_in[7];   // [0]=src(b), [1]=dst(a)
  const int E = in_sizes[6] / 2;
  const int N = in_sizes[0] / D;             // 8192

  char* p = (char*)d_ws;
  ushort* xa16    = (ushort*)p;   p += (size_t)N * D * 2;
  ushort* xb16    = (ushort*)p;   p += (size_t)N * D * 2;
  ushort* ctx0a   = (ushort*)p;   p += (size_t)N * D * 2;
  ushort* ctx0b   = (ushort*)p;   p += (size_t)N * D * 2;
  ushort* W16a    = (ushort*)p;   p += (size_t)D * D * 2;
  ushort* W16b    = (ushort*)p;   p += (size_t)D * D * 2;
  unsigned* scratch = (unsigned*)p; p += (size_t)2 * BK * CH * CAP * 4;  // 8MB
  unsigned* ccnt  = (unsigned*)p; p += (size_t)2 * BK * CH * 4;          // 256KB

  prep_kernel<<<16, 256, 0, stream>>>(W_a, W_b, W16a, W16b, (float*)d_out);

  linear_bin<<<2 * (N / 64) + 2 * CH, 256, 0, stream>>>(
      x_a, x_b, W16a, W16b, b_a, b_b, xa16, xb16, ctx0a, ctx0b,
      e_ba, e_ab, scratch, ccnt, E, N);

  loss_fused<<<2 * (N / 16), 256, 0, stream>>>(
      xa16, xb16, ctx0a, ctx0b, scratch, ccnt, (float*)d_out, N);
}

// Round 9
// 56.364 us; speedup vs baseline: 3.1987x; 1.1110x over previous
//
#include <hip/hip_runtime.h>
#include <math.h>

#define D 128
#define DEG 64           // per-node slot capacity (mean degree 32)
#define BK 128           // dst buckets per direction (64 nodes/bucket)
#define CH 256           // edge chunks per direction (1024 edges/chunk)
#define CAP 32           // slots per (bucket,chunk) cell; mean 8, P(>32)~1e-13

typedef __attribute__((ext_vector_type(8))) short bf8;
typedef __attribute__((ext_vector_type(4))) float f4;

__device__ __forceinline__ unsigned hash_u32(unsigned x){
  x ^= x >> 16; x *= 0x7feb352du; x ^= x >> 15; x *= 0x846ca68bu; x ^= x >> 16;
  return x;
}
__device__ __forceinline__ unsigned f2bfbits(float f){
  unsigned u = __float_as_uint(f);
  return (u + 0x7fffu + ((u >> 16) & 1u)) >> 16;   // RNE bf16
}
__device__ __forceinline__ float bflo(unsigned u){ return __uint_as_float(u << 16); }
__device__ __forceinline__ float bfhi(unsigned u){ return __uint_as_float(u & 0xffff0000u); }
__device__ __forceinline__ uint4 pack8(float4 v0, float4 v1){
  uint4 o;
  o.x = f2bfbits(v0.x) | (f2bfbits(v0.y) << 16);
  o.y = f2bfbits(v0.z) | (f2bfbits(v0.w) << 16);
  o.z = f2bfbits(v1.x) | (f2bfbits(v1.y) << 16);
  o.w = f2bfbits(v1.z) | (f2bfbits(v1.w) << 16);
  return o;
}
// XCD-aware type partition (perf heuristic; bijective, correctness-neutral).
__device__ __forceinline__ int xcd_remap(int bid, int jobs_per_type){
  if (jobs_per_type & 3) return bid;
  const int xcd = bid & 7, slot = bid >> 3;
  const int q = jobs_per_type >> 2;
  return (xcd >> 2) * jobs_per_type + (xcd & 3) * q + slot;
}

struct LinS { alignas(16) ushort Ws[64 * 128]; alignas(16) ushort As[4][16 * 128]; }; // 32KB
struct BinS { int hist[BK]; int ex[BK]; int cur[BK]; unsigned buf[1024]; };           // 5.5KB
union SharedU { LinS lin; BinS bin; };

// ---- K1: linear (256 blk, W staged from fp32) || fixed-slot bin (512 blk)
//          || 1 block zeroing out. No prep kernel, no global atomics anywhere.
__global__ __launch_bounds__(256)
void linear_bin(const float* __restrict__ xa, const float* __restrict__ xb,
                const float* __restrict__ Wa, const float* __restrict__ Wb,
                const float* __restrict__ ba, const float* __restrict__ bb,
                ushort* __restrict__ x16a, ushort* __restrict__ x16b,
                ushort* __restrict__ oa, ushort* __restrict__ ob,
                const int* __restrict__ e_ba, const int* __restrict__ e_ab,
                unsigned* __restrict__ scratch, unsigned* __restrict__ ccnt,
                float* __restrict__ out0, int E, int N){
  const int LB = 2 * (N >> 6);                   // 256 linear blocks (LB%8==0)
  __shared__ SharedU sh;

  if ((int)blockIdx.x < LB){
    // ---------------- ctx0 = bf16(x @ W^T + b) via MFMA ----------------
    const int nb64 = N >> 6;
    const int jid = xcd_remap((int)blockIdx.x, nb64);
    const int type = jid >= nb64;
    const int r0 = (jid - (type ? nb64 : 0)) << 6;
    const float* __restrict__ x = type ? xb : xa;
    const float* __restrict__ W = type ? Wb : Wa;
    const float* __restrict__ bias = type ? bb : ba;
    ushort* __restrict__ x16 = type ? x16b : x16a;
    ushort* __restrict__ out = type ? ob : oa;
    const int t = threadIdx.x, w = t >> 6, l = t & 63;

    #define STAGE_W(H)                                                        \
    {                                                                         \
      _Pragma("unroll")                                                       \
      for (int i = 0; i < 4; i++){                                            \
        const int cid = i * 256 + t;                                          \
        const int col = cid >> 4, kq = cid & 15;                              \
        const int gcol = (H) * 64 + col;                                      \
        const float4 v0 = *(const float4*)(W + (gcol << 7) + (kq << 3));      \
        const float4 v1 = *(const float4*)(W + (gcol << 7) + (kq << 3) + 4);  \
        *(uint4*)&sh.lin.Ws[(col << 7) + ((kq ^ (col & 7)) << 3)] = pack8(v0, v1); \
      }                                                                       \
    }

    #pragma unroll
    for (int i = 0; i < 4; i++){
      const int cid = i * 64 + l;
      const int row = cid >> 4, kq = cid & 15;
      const size_t gr = (size_t)(r0 + w * 16 + row);
      const float4 v0 = *(const float4*)(x + (gr << 7) + (kq << 3));
      const float4 v1 = *(const float4*)(x + (gr << 7) + (kq << 3) + 4);
      const uint4 o = pack8(v0, v1);
      *(uint4*)&sh.lin.As[w][(row << 7) + ((kq ^ (row & 7)) << 3)] = o;
      *(uint4*)(x16 + (gr << 7) + (kq << 3)) = o;  // 1KB/instr coalesced
    }
    STAGE_W(0)
    __syncthreads();

    const int rloc = l & 15, kg = l >> 4;
    bf8 af[4];
    #pragma unroll
    for (int ks = 0; ks < 4; ks++){
      const int kq = ks * 4 + kg;
      af[ks] = *(const bf8*)&sh.lin.As[w][(rloc << 7) + ((kq ^ (rloc & 7)) << 3)];
    }
    #pragma unroll
    for (int h = 0; h < 2; h++){
      if (h == 1){
        __syncthreads();
        STAGE_W(1)
        __syncthreads();
      }
      #pragma unroll
      for (int c2 = 0; c2 < 4; c2++){
        const int ct = h * 4 + c2;
        f4 acc = {0.f, 0.f, 0.f, 0.f};
        const int col = ct * 16 + rloc;
        const int lcol = c2 * 16 + rloc;          // (col&7)==(lcol&7)
        #pragma unroll
        for (int ks = 0; ks < 4; ks++){
          const int kq = ks * 4 + kg;
          const bf8 bfr = *(const bf8*)&sh.lin.Ws[(lcol << 7) + ((kq ^ (lcol & 7)) << 3)];
          acc = __builtin_amdgcn_mfma_f32_16x16x32_bf16(af[ks], bfr, acc, 0, 0, 0);
        }
        const float bv = bias[col];
        #pragma unroll
        for (int r = 0; r < 4; r++){
          const int row = r0 + w * 16 + kg * 4 + r;
          out[((size_t)row << 7) + col] = (ushort)f2bfbits(acc[r] + bv);
        }
      }
    }
    #undef STAGE_W
  } else if ((int)blockIdx.x < LB + 2 * CH){
    // -------- fixed-slot binning: block owns (dir, chunk), 0 glb atomics ---
    const int sbid = (int)blockIdx.x - LB;       // 0..511
    const int d = sbid >> 8, chunk = sbid & 255;
    const int* __restrict__ e = d ? e_ab : e_ba;
    const int t = threadIdx.x;
    if (t < BK) sh.bin.hist[t] = 0;
    __syncthreads();

    int ds[4], ss[4];
    const int base = chunk * 1024;
    #pragma unroll
    for (int k = 0; k < 4; k++){
      const int i = base + k * 256 + t;
      const bool ok = i < E;
      ds[k] = ok ? e[E + i] : -1;
      ss[k] = ok ? e[i] : 0;
      if (ok) atomicAdd(&sh.bin.hist[ds[k] >> 6], 1);   // LDS atomic
    }
    __syncthreads();
    if (t < BK) sh.bin.ex[t] = sh.bin.hist[t];
    __syncthreads();
    for (int off = 1; off < BK; off <<= 1){      // Hillis-Steele over 128 bins
      int v = 0;
      if (t < BK && t >= off) v = sh.bin.ex[t - off];
      __syncthreads();
      if (t < BK) sh.bin.ex[t] += v;
      __syncthreads();
    }
    if (t < BK){ sh.bin.ex[t] -= sh.bin.hist[t]; sh.bin.cur[t] = sh.bin.ex[t]; }
    __syncthreads();
    #pragma unroll
    for (int k = 0; k < 4; k++){
      if (ds[k] >= 0){
        const int p = atomicAdd(&sh.bin.cur[ds[k] >> 6], 1);   // LDS atomic
        sh.bin.buf[p] = (unsigned)ss[k] | ((unsigned)ds[k] << 13);
      }
    }
    __syncthreads();
    int nv = E - base; nv = nv < 0 ? 0 : (nv > 1024 ? 1024 : nv);
    if (t < BK) ccnt[(size_t)(d * BK + t) * CH + chunk] = (unsigned)min(sh.bin.hist[t], CAP);
    for (int s = t; s < nv; s += 256){
      const unsigned v = sh.bin.buf[s];
      const int bkt = (int)(v >> 19);            // dst>>6
      const int gp = s - sh.bin.ex[bkt];
      if (gp < CAP) scratch[((size_t)(d * BK + bkt) * CH + chunk) * CAP + gp] = v;
    }
  } else {
    if (threadIdx.x == 0) *out0 = 0.0f;
  }
}

// ---- K2: per-bucket CSR build from cells; each cell read EXACTLY ONCE -----
// (r8's loss scanned cells with 16x amplification -> 45us; this reads the 8MB
// of cells once at BW, compacts in LDS, writes cnt+csr fully coalesced.)
__global__ __launch_bounds__(256)
void csr_build(const unsigned* __restrict__ scratch, const unsigned* __restrict__ ccnt,
               int* __restrict__ cnt, int* __restrict__ csr, int N){
  const int bid = (int)blockIdx.x;               // 0..255
  const int d = bid >> 7, bkt = bid & 127;
  const int t = threadIdx.x;
  __shared__ int slots[64 * DEG];                // 16KB
  __shared__ int lcnt[64];
  __shared__ unsigned cc[CH];
  if (t < 64) lcnt[t] = 0;
  const size_t cellbase = (size_t)(d * BK + bkt) * CH;
  if (t < CH) cc[t] = ccnt[cellbase + t];
  __syncthreads();
  for (int i = t; i < CH * CAP; i += 256){       // 32KB contiguous read
    const int cell = i >> 5, slot = i & (CAP - 1);
    if (slot < (int)cc[cell]){
      const unsigned v = scratch[cellbase * CAP + i];
      const int node = (int)((v >> 13) & 63u);
      const int p = atomicAdd(&lcnt[node], 1);   // LDS atomic
      if (p < DEG) slots[node * DEG + p] = (int)(v & 8191u);
    }
  }
  __syncthreads();
  const int nodebase = d * N + bkt * 64;
  if (t < 64) cnt[nodebase + t] = lcnt[t];       // true degree (loss caps at DEG)
  const size_t cbase = (size_t)nodebase * DEG;
  for (int j = t; j < 64 * DEG; j += 256)
    csr[cbase + j] = slots[j];                   // 16KB contiguous, full lines
}

// ---- K3: fused gather-mean + contrastive loss (r5-verified, csr-based) ----
__global__ __launch_bounds__(256)
void loss_fused(const ushort* __restrict__ xa, const ushort* __restrict__ xb,
                const ushort* __restrict__ ctx0a, const ushort* __restrict__ ctx0b,
                const int* __restrict__ cnt, const int* __restrict__ csr,
                float* __restrict__ out, int n){
  const int nb = n >> 4;                          // 512 jobs per type
  const int jid = xcd_remap((int)blockIdx.x, nb); // XCDs 0-3: type 0, XCDs 4-7: type 1
  const int type = jid >= nb;
  const int r0 = (jid - (type ? nb : 0)) << 4;
  const ushort* __restrict__ x    = type ? xb : xa;
  const ushort* __restrict__ feat = type ? ctx0a : ctx0b;
  const int nodebase = type ? n : 0;
  const int t = threadIdx.x, w = t >> 6, l = t & 63;
  const int sg = l >> 4, q = l & 15;

  __shared__ alignas(16) ushort A[16 * 128];
  __shared__ float lpos[16];
  __shared__ float2 part[4][16];

  const unsigned h = hash_u32((unsigned)jid * 2654435761u + 0x9E3779B9u);
  const unsigned bo = h & 8191u;
  const unsigned aa = (((h >> 13) & 4095u) << 1) | 1u;

  { // ---- phase 1: gather-mean for node row = w*4+sg ----------------------
    const int row = w * 4 + sg;
    const int node = nodebase + r0 + row;
    const int c = min(cnt[node], DEG);
    const size_t sbase = (size_t)node * DEG;
    int sl0 = csr[sbase + q];
    int sl1 = csr[sbase + 16 + q];
    int sl2 = csr[sbase + 32 + q];
    int sl3 = csr[sbase + 48 + q];

    float a0=0.f,a1=0.f,a2=0.f,a3=0.f,a4=0.f,a5=0.f,a6=0.f,a7=0.f;
    const int lbase = l & 48;
    #define GMEAN_CHUNK(SL, J)                                                 \
    if (c > (J)*16){                                                           \
      _Pragma("unroll")                                                        \
      for (int i = 0; i < 16; i++){                                            \
        const int raw = __shfl((SL), lbase | i, 64);                           \
        const bool ok = (J)*16 + i < c;                                        \
        const int src = ok ? raw : 0;                                          \
        const float wt = ok ? 1.0f : 0.0f;                                     \
        const uint4 v = *(const uint4*)(feat + ((size_t)src << 7) + (q << 3)); \
        a0 += wt*bflo(v.x); a1 += wt*bfhi(v.x); a2 += wt*bflo(v.y); a3 += wt*bfhi(v.y); \
        a4 += wt*bflo(v.z); a5 += wt*bfhi(v.z); a6 += wt*bflo(v.w); a7 += wt*bfhi(v.w); \
      }                                                                        \
    }
    GMEAN_CHUNK(sl0, 0) GMEAN_CHUNK(sl1, 1) GMEAN_CHUNK(sl2, 2) GMEAN_CHUNK(sl3, 3)
    #undef GMEAN_CHUNK

    const float inv = 1.0f / (float)(c > 1 ? c : 1);
    uint4 o;
    o.x = f2bfbits(a0*inv) | (f2bfbits(a1*inv) << 16);
    o.y = f2bfbits(a2*inv) | (f2bfbits(a3*inv) << 16);
    o.z = f2bfbits(a4*inv) | (f2bfbits(a5*inv) << 16);
    o.w = f2bfbits(a6*inv) | (f2bfbits(a7*inv) << 16);
    *(uint4*)&A[(row << 7) + ((q ^ (row & 7)) << 3)] = o;
  }
  __syncthreads();

  // ---- phase 2: MFMA tiles with direct-global B, online LSE ----
  const int nloc = l & 15, kg = l >> 4;
  bf8 af[4];
  #pragma unroll
  for (int ks = 0; ks < 4; ks++){
    const int kq = ks * 4 + kg;
    af[ks] = *(const bf8*)&A[(nloc << 7) + ((kq ^ (nloc & 7)) << 3)];
  }

  float M0=-1e30f, M1=-1e30f, M2=-1e30f, M3=-1e30f;
  float S0=0.f, S1=0.f, S2=0.f, S3=0.f;

  for (int tile = w; tile < 17; tile += 4){
    const int colid = tile * 16 + nloc;
    const int jn = colid - 16;
    const bool isneg = colid >= 16;
    const int g = isneg ? (int)((aa * (unsigned)jn + bo) & 8191u) : (r0 + colid);

    const ushort* __restrict__ xr = x + ((size_t)g << 7);
    f4 acc = {0.f, 0.f, 0.f, 0.f};
    #pragma unroll
    for (int ks = 0; ks < 4; ks++){
      const bf8 bfr = *(const bf8*)(xr + ks * 32 + kg * 8);
      acc = __builtin_amdgcn_mfma_f32_16x16x32_bf16(af[ks], bfr, acc, 0, 0, 0);
    }
    #pragma unroll
    for (int r = 0; r < 4; r++){
      const int row = kg * 4 + r;
      const bool valid = isneg ? (jn < 255 && g != r0 + row) : (colid == row);
      const float v = acc[r] * 10.0f;
      if (!isneg && colid == row) lpos[row] = v;
      float* Mp; float* Sp;
      if (r == 0){ Mp = &M0; Sp = &S0; } else if (r == 1){ Mp = &M1; Sp = &S1; }
      else if (r == 2){ Mp = &M2; Sp = &S2; } else { Mp = &M3; Sp = &S3; }
      if (valid){
        const float Mn = fmaxf(*Mp, v);
        *Sp = *Sp * __expf(*Mp - Mn) + __expf(v - Mn);
        *Mp = Mn;
      }
    }
  }

  #define MERGE_LANES(MV, SV)                          \
  {                                                    \
    _Pragma("unroll")                                  \
    for (int o = 1; o < 16; o <<= 1){                  \
      const float Mo = __shfl_xor((MV), o);            \
      const float So = __shfl_xor((SV), o);            \
      const float Mn = fmaxf((MV), Mo);                \
      (SV) = (SV) * __expf((MV) - Mn) + So * __expf(Mo - Mn); \
      (MV) = Mn;                                       \
    }                                                  \
  }
  MERGE_LANES(M0, S0) MERGE_LANES(M1, S1) MERGE_LANES(M2, S2) MERGE_LANES(M3, S3)
  #undef MERGE_LANES

  if (nloc == 0){
    part[w][kg * 4 + 0] = make_float2(M0, S0);
    part[w][kg * 4 + 1] = make_float2(M1, S1);
    part[w][kg * 4 + 2] = make_float2(M2, S2);
    part[w][kg * 4 + 3] = make_float2(M3, S3);
  }
  __syncthreads();

  if (w == 0 && l < 16){
    const int row = l;
    float Mm = -1e30f, Ss = 0.f;
    #pragma unroll
    for (int j = 0; j < 4; j++){
      const float2 ps = part[j][row];
      const float Mn = fmaxf(Mm, ps.x);
      Ss = Ss * __expf(Mm - Mn) + ps.y * __expf(ps.x - Mn);
      Mm = Mn;
    }
    float term = Mm + __logf(Ss) - lpos[row];
    #pragma unroll
    for (int o = 8; o >= 1; o >>= 1) term += __shfl_xor(term, o);
    if (l == 0) atomicAdd(out, term / (logf(256.0f) * (float)(2 * n)));
  }
}

extern "C" void kernel_launch(void* const* d_in, const int* in_sizes, int n_in,
                              void* d_out, int out_size, void* d_ws, size_t ws_size,
                              hipStream_t stream) {
  const float* x_a = (const float*)d_in[0];
  const float* x_b = (const float*)d_in[1];
  const float* W_a = (const float*)d_in[2];
  const float* b_a = (const float*)d_in[3];
  const float* W_b = (const float*)d_in[4];
  const float* b_b = (const float*)d_in[5];
  const int*   e_ab = (const int*)d_in[6];   // [2,E]: [0]=src(a), [1]=dst(b)
  const int*   e_ba = (const int*)d_in[7];   // [0]=src(b), [1]=dst(a)
  const int E = in_sizes[6] / 2;
  const int N = in_sizes[0] / D;             // 8192

  char* p = (char*)d_ws;
  ushort* xa16    = (ushort*)p;   p += (size_t)N * D * 2;
  ushort* xb16    = (ushort*)p;   p += (size_t)N * D * 2;
  ushort* ctx0a   = (ushort*)p;   p += (size_t)N * D * 2;
  ushort* ctx0b   = (ushort*)p;   p += (size_t)N * D * 2;
  unsigned* scratch = (unsigned*)p; p += (size_t)2 * BK * CH * CAP * 4;  // 8MB
  unsigned* ccnt  = (unsigned*)p; p += (size_t)2 * BK * CH * 4;          // 256KB
  int*    cnt     = (int*)p;      p += (size_t)2 * N * 4;                // 64KB
  int*    csr     = (int*)p;      p += (size_t)2 * N * DEG * 4;          // 4MB

  linear_bin<<<2 * (N / 64) + 2 * CH + 1, 256, 0, stream>>>(
      x_a, x_b, W_a, W_b, b_a, b_b, xa16, xb16, ctx0a, ctx0b,
      e_ba, e_ab, scratch, ccnt, (float*)d_out, E, N);

  csr_build<<<2 * BK, 256, 0, stream>>>(scratch, ccnt, cnt, csr, N);

  loss_fused<<<2 * (N / 16), 256, 0, stream>>>(
      xa16, xb16, ctx0a, ctx0b, cnt, csr, (float*)d_out, N);
}

// Round 10
// 45.226 us; speedup vs baseline: 3.9864x; 1.2463x over previous
//
#include <hip/hip_runtime.h>
#include <math.h>

#define D 128
#define DEG 64           // per-node slot capacity (mean degree 32)
#define BK 128           // dst buckets per direction (64 nodes/bucket)
#define CH 256           // edge chunks per direction (1024 edges/chunk)
#define CAP 32           // slots per (bucket,chunk) cell; mean 8, P(>32)~1e-13

typedef __attribute__((ext_vector_type(8))) short bf8;
typedef __attribute__((ext_vector_type(4))) float f4;

__device__ __forceinline__ unsigned hash_u32(unsigned x){
  x ^= x >> 16; x *= 0x7feb352du; x ^= x >> 15; x *= 0x846ca68bu; x ^= x >> 16;
  return x;
}
__device__ __forceinline__ unsigned f2bfbits(float f){
  unsigned u = __float_as_uint(f);
  return (u + 0x7fffu + ((u >> 16) & 1u)) >> 16;   // RNE bf16
}
__device__ __forceinline__ float bflo(unsigned u){ return __uint_as_float(u << 16); }
__device__ __forceinline__ float bfhi(unsigned u){ return __uint_as_float(u & 0xffff0000u); }
__device__ __forceinline__ uint4 pack8(float4 v0, float4 v1){
  uint4 o;
  o.x = f2bfbits(v0.x) | (f2bfbits(v0.y) << 16);
  o.y = f2bfbits(v0.z) | (f2bfbits(v0.w) << 16);
  o.z = f2bfbits(v1.x) | (f2bfbits(v1.y) << 16);
  o.w = f2bfbits(v1.z) | (f2bfbits(v1.w) << 16);
  return o;
}
// XCD-aware type partition (perf heuristic; bijective, correctness-neutral).
__device__ __forceinline__ int xcd_remap(int bid, int jobs_per_type){
  if (jobs_per_type & 3) return bid;
  const int xcd = bid & 7, slot = bid >> 3;
  const int q = jobs_per_type >> 2;
  return (xcd >> 2) * jobs_per_type + (xcd & 3) * q + slot;
}

struct LinS { alignas(16) ushort Ws[64 * 128]; alignas(16) ushort As[4][16 * 128]; }; // 32KB
struct BinS { int hist[BK]; int ex[BK]; int cur[BK]; int w0tot; unsigned buf[1024]; };
union SharedU { LinS lin; BinS bin; };

// ---- K1: linear (256 blk) || fixed-slot bin (512 blk) || 1 out-zero block -
__global__ __launch_bounds__(256)
void linear_bin(const float* __restrict__ xa, const float* __restrict__ xb,
                const float* __restrict__ Wa, const float* __restrict__ Wb,
                const float* __restrict__ ba, const float* __restrict__ bb,
                ushort* __restrict__ x16a, ushort* __restrict__ x16b,
                ushort* __restrict__ oa, ushort* __restrict__ ob,
                const int* __restrict__ e_ba, const int* __restrict__ e_ab,
                unsigned* __restrict__ scratch, unsigned* __restrict__ ccnt,
                float* __restrict__ out0, int E, int N){
  const int LB = 2 * (N >> 6);                   // 256 linear blocks (LB%8==0)
  __shared__ SharedU sh;

  if ((int)blockIdx.x < LB){
    // ---------------- ctx0 = bf16(x @ W^T + b) via MFMA ----------------
    const int nb64 = N >> 6;
    const int jid = xcd_remap((int)blockIdx.x, nb64);
    const int type = jid >= nb64;
    const int r0 = (jid - (type ? nb64 : 0)) << 6;
    const float* __restrict__ x = type ? xb : xa;
    const float* __restrict__ W = type ? Wb : Wa;
    const float* __restrict__ bias = type ? bb : ba;
    ushort* __restrict__ x16 = type ? x16b : x16a;
    ushort* __restrict__ out = type ? ob : oa;
    const int t = threadIdx.x, w = t >> 6, l = t & 63;

    #define STAGE_W(H)                                                        \
    {                                                                         \
      _Pragma("unroll")                                                       \
      for (int i = 0; i < 4; i++){                                            \
        const int cid = i * 256 + t;                                          \
        const int col = cid >> 4, kq = cid & 15;                              \
        const int gcol = (H) * 64 + col;                                      \
        const float4 v0 = *(const float4*)(W + (gcol << 7) + (kq << 3));      \
        const float4 v1 = *(const float4*)(W + (gcol << 7) + (kq << 3) + 4);  \
        *(uint4*)&sh.lin.Ws[(col << 7) + ((kq ^ (col & 7)) << 3)] = pack8(v0, v1); \
      }                                                                       \
    }

    #pragma unroll
    for (int i = 0; i < 4; i++){
      const int cid = i * 64 + l;
      const int row = cid >> 4, kq = cid & 15;
      const size_t gr = (size_t)(r0 + w * 16 + row);
      const float4 v0 = *(const float4*)(x + (gr << 7) + (kq << 3));
      const float4 v1 = *(const float4*)(x + (gr << 7) + (kq << 3) + 4);
      const uint4 o = pack8(v0, v1);
      *(uint4*)&sh.lin.As[w][(row << 7) + ((kq ^ (row & 7)) << 3)] = o;
      *(uint4*)(x16 + (gr << 7) + (kq << 3)) = o;  // 1KB/instr coalesced
    }
    STAGE_W(0)
    __syncthreads();

    const int rloc = l & 15, kg = l >> 4;
    bf8 af[4];
    #pragma unroll
    for (int ks = 0; ks < 4; ks++){
      const int kq = ks * 4 + kg;
      af[ks] = *(const bf8*)&sh.lin.As[w][(rloc << 7) + ((kq ^ (rloc & 7)) << 3)];
    }
    #pragma unroll
    for (int h = 0; h < 2; h++){
      if (h == 1){
        __syncthreads();
        STAGE_W(1)
        __syncthreads();
      }
      #pragma unroll
      for (int c2 = 0; c2 < 4; c2++){
        const int ct = h * 4 + c2;
        f4 acc = {0.f, 0.f, 0.f, 0.f};
        const int col = ct * 16 + rloc;
        const int lcol = c2 * 16 + rloc;          // (col&7)==(lcol&7)
        #pragma unroll
        for (int ks = 0; ks < 4; ks++){
          const int kq = ks * 4 + kg;
          const bf8 bfr = *(const bf8*)&sh.lin.Ws[(lcol << 7) + ((kq ^ (lcol & 7)) << 3)];
          acc = __builtin_amdgcn_mfma_f32_16x16x32_bf16(af[ks], bfr, acc, 0, 0, 0);
        }
        const float bv = bias[col];
        #pragma unroll
        for (int r = 0; r < 4; r++){
          const int row = r0 + w * 16 + kg * 4 + r;
          out[((size_t)row << 7) + col] = (ushort)f2bfbits(acc[r] + bv);
        }
      }
    }
    #undef STAGE_W
  } else if ((int)blockIdx.x < LB + 2 * CH){
    // -------- fixed-slot binning: block owns (dir, chunk), 0 glb atomics ---
    const int sbid = (int)blockIdx.x - LB;       // 0..511
    const int d = sbid >> 8, chunk = sbid & 255;
    const int* __restrict__ e = d ? e_ab : e_ba;
    const int t = threadIdx.x;
    if (t < BK) sh.bin.hist[t] = 0;
    __syncthreads();

    int ds[4], ss[4];
    const int base = chunk * 1024;
    #pragma unroll
    for (int k = 0; k < 4; k++){
      const int i = base + k * 256 + t;
      const bool ok = i < E;
      ds[k] = ok ? e[E + i] : -1;
      ss[k] = ok ? e[i] : 0;
      if (ok) atomicAdd(&sh.bin.hist[ds[k] >> 6], 1);   // LDS atomic
    }
    __syncthreads();
    // 128-bin inclusive scan via 2-wave shfl (replaces 14-sync Hillis-Steele)
    if (t < BK){
      int v = sh.bin.hist[t];
      #pragma unroll
      for (int off = 1; off < 64; off <<= 1){
        const int u = __shfl_up(v, off, 64);
        if ((t & 63) >= off) v += u;
      }
      if (t == 63) sh.bin.w0tot = v;
      sh.bin.ex[t] = v;                           // wave-local inclusive
    }
    __syncthreads();
    if (t < BK){
      int v = sh.bin.ex[t];
      if (t >= 64) v += sh.bin.w0tot;
      const int e0 = v - sh.bin.hist[t];          // exclusive start
      sh.bin.ex[t] = e0; sh.bin.cur[t] = e0;
    }
    __syncthreads();
    #pragma unroll
    for (int k = 0; k < 4; k++){
      if (ds[k] >= 0){
        const int p = atomicAdd(&sh.bin.cur[ds[k] >> 6], 1);   // LDS atomic
        sh.bin.buf[p] = (unsigned)ss[k] | ((unsigned)ds[k] << 13);
      }
    }
    __syncthreads();
    int nv = E - base; nv = nv < 0 ? 0 : (nv > 1024 ? 1024 : nv);
    if (t < BK) ccnt[(size_t)(d * BK + t) * CH + chunk] = (unsigned)min(sh.bin.hist[t], CAP);
    for (int s = t; s < nv; s += 256){
      const unsigned v = sh.bin.buf[s];
      const int bkt = (int)(v >> 19);            // dst>>6
      const int gp = s - sh.bin.ex[bkt];
      if (gp < CAP) scratch[((size_t)(d * BK + bkt) * CH + chunk) * CAP + gp] = v;
    }
  } else {
    if (threadIdx.x == 0) *out0 = 0.0f;
  }
}

// ---- K2: 512 blk x 512 thr x 32 rows: cell-scan (2x amp, vec4) + gather +
//          two independent 16-row loss groups, bit-identical to r9 numerics --
__global__ __launch_bounds__(512, 4)
void loss_fused(const ushort* __restrict__ xa, const ushort* __restrict__ xb,
                const ushort* __restrict__ ctx0a, const ushort* __restrict__ ctx0b,
                const unsigned* __restrict__ scratch, const unsigned* __restrict__ ccnt,
                float* __restrict__ out, int n){
  const int nb = n >> 5;                          // 256 jobs per type (32 rows)
  const int jid = xcd_remap((int)blockIdx.x, nb); // XCDs 0-3: type 0, 4-7: type 1
  const int type = jid >= nb;
  const int j32 = jid - (type ? nb : 0);
  const int r0 = j32 << 5;                        // within-type row base
  const ushort* __restrict__ x    = type ? xb : xa;
  const ushort* __restrict__ feat = type ? ctx0a : ctx0b;  // src-side features
  const int t = threadIdx.x, w8 = t >> 6, l = t & 63;
  const int sg = l >> 4, q = l & 15;

  __shared__ alignas(16) ushort A[32 * 128];      // 8KB
  __shared__ float lpos[32];
  __shared__ float2 part[8][16];
  __shared__ int list[32 * DEG];                  // 8KB
  __shared__ int lcnt[32];
  __shared__ unsigned cc[CH];

  if (t < 32) lcnt[t] = 0;
  const int bkt = r0 >> 6;
  const size_t cellbase = (size_t)(type * BK + bkt) * CH;
  if (t < CH) cc[t] = ccnt[cellbase + t];
  __syncthreads();

  { // phase 0: vec4 masked scan of bucket cells; keep dl in [0,32)
    for (int i4 = t * 4; i4 < CH * CAP; i4 += 512 * 4){
      const uint4 v4 = *(const uint4*)(scratch + cellbase * CAP + i4);
      const int cell = i4 >> 5;
      const int cn = (int)cc[cell];
      const int s0 = i4 & 31;
      #pragma unroll
      for (int j = 0; j < 4; j++){
        if (s0 + j < cn){
          const unsigned v = (&v4.x)[j];
          const int dl = (int)((v >> 13) & 8191u) - r0;
          if ((unsigned)dl < 32u){
            const int p = atomicAdd(&lcnt[dl], 1);
            if (p < DEG) list[dl * DEG + p] = (int)(v & 8191u);
          }
        }
      }
    }
  }
  __syncthreads();

  { // phase 1: gather-mean, row = w8*4+sg in [0,32)
    const int row = w8 * 4 + sg;
    const int c = min(lcnt[row], DEG);
    const int lb2 = row * DEG;
    int sl0 = list[lb2 + q];
    int sl1 = list[lb2 + 16 + q];
    int sl2 = list[lb2 + 32 + q];
    int sl3 = list[lb2 + 48 + q];

    float a0=0.f,a1=0.f,a2=0.f,a3=0.f,a4=0.f,a5=0.f,a6=0.f,a7=0.f;
    const int lbase = l & 48;
    #define GMEAN_CHUNK(SL, J)                                                 \
    if (c > (J)*16){                                                           \
      _Pragma("unroll")                                                        \
      for (int i = 0; i < 16; i++){                                            \
        const int raw = __shfl((SL), lbase | i, 64);                           \
        const bool ok = (J)*16 + i < c;                                        \
        const int src = ok ? raw : 0;                                          \
        const float wt = ok ? 1.0f : 0.0f;                                     \
        const uint4 v = *(const uint4*)(feat + ((size_t)src << 7) + (q << 3)); \
        a0 += wt*bflo(v.x); a1 += wt*bfhi(v.x); a2 += wt*bflo(v.y); a3 += wt*bfhi(v.y); \
        a4 += wt*bflo(v.z); a5 += wt*bfhi(v.z); a6 += wt*bflo(v.w); a7 += wt*bfhi(v.w); \
      }                                                                        \
    }
    GMEAN_CHUNK(sl0, 0) GMEAN_CHUNK(sl1, 1) GMEAN_CHUNK(sl2, 2) GMEAN_CHUNK(sl3, 3)
    #undef GMEAN_CHUNK

    const float inv = 1.0f / (float)(c > 1 ? c : 1);
    uint4 o;
    o.x = f2bfbits(a0*inv) | (f2bfbits(a1*inv) << 16);
    o.y = f2bfbits(a2*inv) | (f2bfbits(a3*inv) << 16);
    o.z = f2bfbits(a4*inv) | (f2bfbits(a5*inv) << 16);
    o.w = f2bfbits(a6*inv) | (f2bfbits(a7*inv) << 16);
    *(uint4*)&A[(row << 7) + ((q ^ (row & 7)) << 3)] = o;
  }
  __syncthreads();

  // phase 2: two independent 16-row groups; group g on waves 4g..4g+3.
  // Hash keyed on the ORIGINAL 16-row job id -> negatives identical to r9.
  const int nloc = l & 15, kg = l >> 4;
  const int group = w8 >> 2, wl = w8 & 3;
  const int r0g = r0 + group * 16;
  const int jid16 = type * (n >> 4) + (j32 << 1) + group;
  const unsigned h = hash_u32((unsigned)jid16 * 2654435761u + 0x9E3779B9u);
  const unsigned bo = h & 8191u;
  const unsigned aa = (((h >> 13) & 4095u) << 1) | 1u;

  bf8 af[4];
  #pragma unroll
  for (int ks = 0; ks < 4; ks++){
    const int kq = ks * 4 + kg;
    af[ks] = *(const bf8*)&A[((group * 16 + nloc) << 7) + ((kq ^ (nloc & 7)) << 3)];
  }

  float M0=-1e30f, M1=-1e30f, M2=-1e30f, M3=-1e30f;
  float S0=0.f, S1=0.f, S2=0.f, S3=0.f;

  for (int tile = wl; tile < 17; tile += 4){
    const int colid = tile * 16 + nloc;
    const int jn = colid - 16;
    const bool isneg = colid >= 16;
    const int g = isneg ? (int)((aa * (unsigned)jn + bo) & 8191u) : (r0g + colid);

    const ushort* __restrict__ xr = x + ((size_t)g << 7);
    f4 acc = {0.f, 0.f, 0.f, 0.f};
    #pragma unroll
    for (int ks = 0; ks < 4; ks++){
      const bf8 bfr = *(const bf8*)(xr + ks * 32 + kg * 8);
      acc = __builtin_amdgcn_mfma_f32_16x16x32_bf16(af[ks], bfr, acc, 0, 0, 0);
    }
    #pragma unroll
    for (int r = 0; r < 4; r++){
      const int row = kg * 4 + r;
      const bool valid = isneg ? (jn < 255 && g != r0g + row) : (colid == row);
      const float v = acc[r] * 10.0f;
      if (!isneg && colid == row) lpos[group * 16 + row] = v;  // tile 0 (wl==0)
      float* Mp; float* Sp;
      if (r == 0){ Mp = &M0; Sp = &S0; } else if (r == 1){ Mp = &M1; Sp = &S1; }
      else if (r == 2){ Mp = &M2; Sp = &S2; } else { Mp = &M3; Sp = &S3; }
      if (valid){
        const float Mn = fmaxf(*Mp, v);
        *Sp = *Sp * __expf(*Mp - Mn) + __expf(v - Mn);
        *Mp = Mn;
      }
    }
  }

  #define MERGE_LANES(MV, SV)                          \
  {                                                    \
    _Pragma("unroll")                                  \
    for (int o = 1; o < 16; o <<= 1){                  \
      const float Mo = __shfl_xor((MV), o);            \
      const float So = __shfl_xor((SV), o);            \
      const float Mn = fmaxf((MV), Mo);                \
      (SV) = (SV) * __expf((MV) - Mn) + So * __expf(Mo - Mn); \
      (MV) = Mn;                                       \
    }                                                  \
  }
  MERGE_LANES(M0, S0) MERGE_LANES(M1, S1) MERGE_LANES(M2, S2) MERGE_LANES(M3, S3)
  #undef MERGE_LANES

  if (nloc == 0){
    part[w8][kg * 4 + 0] = make_float2(M0, S0);
    part[w8][kg * 4 + 1] = make_float2(M1, S1);
    part[w8][kg * 4 + 2] = make_float2(M2, S2);
    part[w8][kg * 4 + 3] = make_float2(M3, S3);
  }
  __syncthreads();

  if ((w8 == 0 || w8 == 4) && l < 16){
    const int row = l;
    float Mm = -1e30f, Ss = 0.f;
    #pragma unroll
    for (int j = 0; j < 4; j++){
      const float2 ps = part[group * 4 + j][row];
      const float Mn = fmaxf(Mm, ps.x);
      Ss = Ss * __expf(Mm - Mn) + ps.y * __expf(ps.x - Mn);
      Mm = Mn;
    }
    float term = Mm + __logf(Ss) - lpos[group * 16 + row];
    #pragma unroll
    for (int o = 8; o >= 1; o >>= 1) term += __shfl_xor(term, o);
    if (l == 0) atomicAdd(out, term / (logf(256.0f) * (float)(2 * n)));
  }
}

extern "C" void kernel_launch(void* const* d_in, const int* in_sizes, int n_in,
                              void* d_out, int out_size, void* d_ws, size_t ws_size,
                              hipStream_t stream) {
  const float* x_a = (const float*)d_in[0];
  const float* x_b = (const float*)d_in[1];
  const float* W_a = (const float*)d_in[2];
  const float* b_a = (const float*)d_in[3];
  const float* W_b = (const float*)d_in[4];
  const float* b_b = (const float*)d_in[5];
  const int*   e_ab = (const int*)d_in[6];   // [2,E]: [0]=src(a), [1]=dst(b)
  const int*   e_ba = (const int*)d_in[7];   // [0]=src(b), [1]=dst(a)
  const int E = in_sizes[6] / 2;
  const int N = in_sizes[0] / D;             // 8192

  char* p = (char*)d_ws;
  ushort* xa16    = (ushort*)p;   p += (size_t)N * D * 2;
  ushort* xb16    = (ushort*)p;   p += (size_t)N * D * 2;
  ushort* ctx0a   = (ushort*)p;   p += (size_t)N * D * 2;
  ushort* ctx0b   = (ushort*)p;   p += (size_t)N * D * 2;
  unsigned* scratch = (unsigned*)p; p += (size_t)2 * BK * CH * CAP * 4;  // 8MB
  unsigned* ccnt  = (unsigned*)p; p += (size_t)2 * BK * CH * 4;          // 256KB

  linear_bin<<<2 * (N / 64) + 2 * CH + 1, 256, 0, stream>>>(
      x_a, x_b, W_a, W_b, b_a, b_b, xa16, xb16, ctx0a, ctx0b,
      e_ba, e_ab, scratch, ccnt, (float*)d_out, E, N);

  loss_fused<<<2 * (N / 32), 512, 0, stream>>>(
      xa16, xb16, ctx0a, ctx0b, scratch, ccnt, (float*)d_out, N);
}

// Round 11
// 45.110 us; speedup vs baseline: 3.9967x; 1.0026x over previous
//
#include <hip/hip_runtime.h>
#include <math.h>

#define D 128
#define DEG 64           // per-node slot capacity (mean degree 32)
#define BK 256           // dst buckets per direction (32 nodes/bucket = 1 loss block)
#define CH 128           // edge chunks per direction (2048 edges/chunk)
#define CAP 32           // slots per (bucket,chunk) cell; mean 8, P(any overflow)~1e-7

typedef __attribute__((ext_vector_type(8))) short bf8;
typedef __attribute__((ext_vector_type(4))) float f4;

__device__ __forceinline__ unsigned hash_u32(unsigned x){
  x ^= x >> 16; x *= 0x7feb352du; x ^= x >> 15; x *= 0x846ca68bu; x ^= x >> 16;
  return x;
}
__device__ __forceinline__ unsigned f2bfbits(float f){
  unsigned u = __float_as_uint(f);
  return (u + 0x7fffu + ((u >> 16) & 1u)) >> 16;   // RNE bf16
}
__device__ __forceinline__ float bflo(unsigned u){ return __uint_as_float(u << 16); }
__device__ __forceinline__ float bfhi(unsigned u){ return __uint_as_float(u & 0xffff0000u); }
__device__ __forceinline__ uint4 pack8(float4 v0, float4 v1){
  uint4 o;
  o.x = f2bfbits(v0.x) | (f2bfbits(v0.y) << 16);
  o.y = f2bfbits(v0.z) | (f2bfbits(v0.w) << 16);
  o.z = f2bfbits(v1.x) | (f2bfbits(v1.y) << 16);
  o.w = f2bfbits(v1.z) | (f2bfbits(v1.w) << 16);
  return o;
}
// XCD-aware type partition (perf heuristic; bijective, correctness-neutral).
__device__ __forceinline__ int xcd_remap(int bid, int jobs_per_type){
  if (jobs_per_type & 3) return bid;
  const int xcd = bid & 7, slot = bid >> 3;
  const int q = jobs_per_type >> 2;
  return (xcd >> 2) * jobs_per_type + (xcd & 3) * q + slot;
}

struct LinS { alignas(16) ushort Ws[64 * 128]; alignas(16) ushort As[4][16 * 128]; }; // 32KB
struct BinS { int hist[BK]; int ex[BK]; int cur[BK]; int wtot[4]; unsigned buf[2048]; }; // ~11.3KB
union SharedU { LinS lin; BinS bin; };

// ---- K1: linear (256 blk) || fixed-slot bin (256 blk) || 1 out-zero block -
__global__ __launch_bounds__(256)
void linear_bin(const float* __restrict__ xa, const float* __restrict__ xb,
                const float* __restrict__ Wa, const float* __restrict__ Wb,
                const float* __restrict__ ba, const float* __restrict__ bb,
                ushort* __restrict__ x16a, ushort* __restrict__ x16b,
                ushort* __restrict__ oa, ushort* __restrict__ ob,
                const int* __restrict__ e_ba, const int* __restrict__ e_ab,
                unsigned* __restrict__ scratch, unsigned* __restrict__ ccnt,
                float* __restrict__ out0, int E, int N){
  const int LB = 2 * (N >> 6);                   // 256 linear blocks (LB%8==0)
  __shared__ SharedU sh;

  if ((int)blockIdx.x < LB){
    // ---------------- ctx0 = bf16(x @ W^T + b) via MFMA ----------------
    const int nb64 = N >> 6;
    const int jid = xcd_remap((int)blockIdx.x, nb64);
    const int type = jid >= nb64;
    const int r0 = (jid - (type ? nb64 : 0)) << 6;
    const float* __restrict__ x = type ? xb : xa;
    const float* __restrict__ W = type ? Wb : Wa;
    const float* __restrict__ bias = type ? bb : ba;
    ushort* __restrict__ x16 = type ? x16b : x16a;
    ushort* __restrict__ out = type ? ob : oa;
    const int t = threadIdx.x, w = t >> 6, l = t & 63;

    #define STAGE_W(H)                                                        \
    {                                                                         \
      _Pragma("unroll")                                                       \
      for (int i = 0; i < 4; i++){                                            \
        const int cid = i * 256 + t;                                          \
        const int col = cid >> 4, kq = cid & 15;                              \
        const int gcol = (H) * 64 + col;                                      \
        const float4 v0 = *(const float4*)(W + (gcol << 7) + (kq << 3));      \
        const float4 v1 = *(const float4*)(W + (gcol << 7) + (kq << 3) + 4);  \
        *(uint4*)&sh.lin.Ws[(col << 7) + ((kq ^ (col & 7)) << 3)] = pack8(v0, v1); \
      }                                                                       \
    }

    #pragma unroll
    for (int i = 0; i < 4; i++){
      const int cid = i * 64 + l;
      const int row = cid >> 4, kq = cid & 15;
      const size_t gr = (size_t)(r0 + w * 16 + row);
      const float4 v0 = *(const float4*)(x + (gr << 7) + (kq << 3));
      const float4 v1 = *(const float4*)(x + (gr << 7) + (kq << 3) + 4);
      const uint4 o = pack8(v0, v1);
      *(uint4*)&sh.lin.As[w][(row << 7) + ((kq ^ (row & 7)) << 3)] = o;
      *(uint4*)(x16 + (gr << 7) + (kq << 3)) = o;  // 1KB/instr coalesced
    }
    STAGE_W(0)
    __syncthreads();

    const int rloc = l & 15, kg = l >> 4;
    bf8 af[4];
    #pragma unroll
    for (int ks = 0; ks < 4; ks++){
      const int kq = ks * 4 + kg;
      af[ks] = *(const bf8*)&sh.lin.As[w][(rloc << 7) + ((kq ^ (rloc & 7)) << 3)];
    }
    #pragma unroll
    for (int h = 0; h < 2; h++){
      if (h == 1){
        __syncthreads();
        STAGE_W(1)
        __syncthreads();
      }
      #pragma unroll
      for (int c2 = 0; c2 < 4; c2++){
        const int ct = h * 4 + c2;
        f4 acc = {0.f, 0.f, 0.f, 0.f};
        const int col = ct * 16 + rloc;
        const int lcol = c2 * 16 + rloc;          // (col&7)==(lcol&7)
        #pragma unroll
        for (int ks = 0; ks < 4; ks++){
          const int kq = ks * 4 + kg;
          const bf8 bfr = *(const bf8*)&sh.lin.Ws[(lcol << 7) + ((kq ^ (lcol & 7)) << 3)];
          acc = __builtin_amdgcn_mfma_f32_16x16x32_bf16(af[ks], bfr, acc, 0, 0, 0);
        }
        const float bv = bias[col];
        #pragma unroll
        for (int r = 0; r < 4; r++){
          const int row = r0 + w * 16 + kg * 4 + r;
          out[((size_t)row << 7) + col] = (ushort)f2bfbits(acc[r] + bv);
        }
      }
    }
    #undef STAGE_W
  } else if ((int)blockIdx.x < LB + 2 * CH){
    // -------- fixed-slot binning: block owns (dir, chunk of 2048) ----------
    const int sbid = (int)blockIdx.x - LB;       // 0..255
    const int d = sbid >> 7, chunk = sbid & 127;
    const int* __restrict__ e = d ? e_ab : e_ba;
    const int t = threadIdx.x;
    #pragma unroll
    for (int i = t; i < BK; i += 256) sh.bin.hist[i] = 0;
    __syncthreads();

    int ds[8], ss[8];
    const int base = chunk * 2048;
    #pragma unroll
    for (int k = 0; k < 8; k++){
      const int i = base + k * 256 + t;
      const bool ok = i < E;
      ds[k] = ok ? e[E + i] : -1;
      ss[k] = ok ? e[i] : 0;
      if (ok) atomicAdd(&sh.bin.hist[ds[k] >> 5], 1);   // LDS atomic, 256 bins
    }
    __syncthreads();
    { // 256-bin inclusive scan: 4 wave-local shfl scans + cross-wave offsets
      int v = sh.bin.hist[t];
      #pragma unroll
      for (int off = 1; off < 64; off <<= 1){
        const int u = __shfl_up(v, off, 64);
        if ((t & 63) >= off) v += u;
      }
      if ((t & 63) == 63) sh.bin.wtot[t >> 6] = v;
      sh.bin.ex[t] = v;
    }
    __syncthreads();
    {
      const int wv = t >> 6;
      int add = 0;
      if (wv > 0) add += sh.bin.wtot[0];
      if (wv > 1) add += sh.bin.wtot[1];
      if (wv > 2) add += sh.bin.wtot[2];
      const int e0 = sh.bin.ex[t] + add - sh.bin.hist[t];  // exclusive start
      sh.bin.ex[t] = e0; sh.bin.cur[t] = e0;
    }
    __syncthreads();
    #pragma unroll
    for (int k = 0; k < 8; k++){
      if (ds[k] >= 0){
        const int p = atomicAdd(&sh.bin.cur[ds[k] >> 5], 1);   // LDS atomic
        sh.bin.buf[p] = (unsigned)ss[k] | ((unsigned)ds[k] << 13);
      }
    }
    __syncthreads();
    int nv = E - base; nv = nv < 0 ? 0 : (nv > 2048 ? 2048 : nv);
    ccnt[((size_t)d * BK + t) * CH + chunk] = (unsigned)min(sh.bin.hist[t], CAP);
    for (int s = t; s < nv; s += 256){
      const unsigned v = sh.bin.buf[s];
      const int bkt = (int)(v >> 18);            // dst>>5
      const int gp = s - sh.bin.ex[bkt];
      if (gp < CAP) scratch[((size_t)(d * BK + bkt) * CH + chunk) * CAP + gp] = v;
    }
  } else {
    if (threadIdx.x == 0) *out0 = 0.0f;
  }
}

// ---- K2: 512 blk x 512 thr x 32 rows. Bucket == block -> 1x-amp contiguous
//          16KB cell scan, then two independent 16-row loss groups (numerics
//          bit-identical to r10/r9). ---------------------------------------
__global__ __launch_bounds__(512, 4)
void loss_fused(const ushort* __restrict__ xa, const ushort* __restrict__ xb,
                const ushort* __restrict__ ctx0a, const ushort* __restrict__ ctx0b,
                const unsigned* __restrict__ scratch, const unsigned* __restrict__ ccnt,
                float* __restrict__ out, int n){
  const int nb = n >> 5;                          // 256 jobs per type (32 rows)
  const int jid = xcd_remap((int)blockIdx.x, nb); // XCDs 0-3: type 0, 4-7: type 1
  const int type = jid >= nb;
  const int j32 = jid - (type ? nb : 0);
  const int r0 = j32 << 5;                        // within-type row base
  const ushort* __restrict__ x    = type ? xb : xa;
  const ushort* __restrict__ feat = type ? ctx0a : ctx0b;  // src-side features
  const int t = threadIdx.x, w8 = t >> 6, l = t & 63;
  const int sg = l >> 4, q = l & 15;

  __shared__ alignas(16) ushort A[32 * 128];      // 8KB
  __shared__ float lpos[32];
  __shared__ float2 part[8][16];
  __shared__ int list[32 * DEG];                  // 8KB
  __shared__ int lcnt[32];
  __shared__ unsigned cc[CH];

  if (t < 32) lcnt[t] = 0;
  const size_t cellbase = (size_t)(type * BK + j32) * CH;  // bucket == j32
  if (t < CH) cc[t] = ccnt[cellbase + t];
  __syncthreads();

  { // phase 0: vec4 scan of OWN bucket only (1x amp, 16KB contiguous)
    for (int i4 = t * 4; i4 < CH * CAP; i4 += 512 * 4){    // 2 iters/thread
      const uint4 v4 = *(const uint4*)(scratch + cellbase * CAP + i4);
      const int cell = i4 >> 5;
      const int cn = (int)cc[cell];
      const int s0 = i4 & 31;
      #pragma unroll
      for (int j = 0; j < 4; j++){
        if (s0 + j < cn){
          const unsigned v = (&v4.x)[j];
          const int dl = (int)((v >> 13) & 8191u) - r0;    // in [0,32) by construction
          const int p = atomicAdd(&lcnt[dl], 1);
          if (p < DEG) list[dl * DEG + p] = (int)(v & 8191u);
        }
      }
    }
  }
  __syncthreads();

  { // phase 1: gather-mean, row = w8*4+sg in [0,32)
    const int row = w8 * 4 + sg;
    const int c = min(lcnt[row], DEG);
    const int lb2 = row * DEG;
    int sl0 = list[lb2 + q];
    int sl1 = list[lb2 + 16 + q];
    int sl2 = list[lb2 + 32 + q];
    int sl3 = list[lb2 + 48 + q];

    float a0=0.f,a1=0.f,a2=0.f,a3=0.f,a4=0.f,a5=0.f,a6=0.f,a7=0.f;
    const int lbase = l & 48;
    #define GMEAN_CHUNK(SL, J)                                                 \
    if (c > (J)*16){                                                           \
      _Pragma("unroll")                                                        \
      for (int i = 0; i < 16; i++){                                            \
        const int raw = __shfl((SL), lbase | i, 64);                           \
        const bool ok = (J)*16 + i < c;                                        \
        const int src = ok ? raw : 0;                                          \
        const float wt = ok ? 1.0f : 0.0f;                                     \
        const uint4 v = *(const uint4*)(feat + ((size_t)src << 7) + (q << 3)); \
        a0 += wt*bflo(v.x); a1 += wt*bfhi(v.x); a2 += wt*bflo(v.y); a3 += wt*bfhi(v.y); \
        a4 += wt*bflo(v.z); a5 += wt*bfhi(v.z); a6 += wt*bflo(v.w); a7 += wt*bfhi(v.w); \
      }                                                                        \
    }
    GMEAN_CHUNK(sl0, 0) GMEAN_CHUNK(sl1, 1) GMEAN_CHUNK(sl2, 2) GMEAN_CHUNK(sl3, 3)
    #undef GMEAN_CHUNK

    const float inv = 1.0f / (float)(c > 1 ? c : 1);
    uint4 o;
    o.x = f2bfbits(a0*inv) | (f2bfbits(a1*inv) << 16);
    o.y = f2bfbits(a2*inv) | (f2bfbits(a3*inv) << 16);
    o.z = f2bfbits(a4*inv) | (f2bfbits(a5*inv) << 16);
    o.w = f2bfbits(a6*inv) | (f2bfbits(a7*inv) << 16);
    *(uint4*)&A[(row << 7) + ((q ^ (row & 7)) << 3)] = o;
  }
  __syncthreads();

  // phase 2: two independent 16-row groups; group g on waves 4g..4g+3.
  // Hash keyed on the ORIGINAL 16-row job id -> negatives identical to r9/r10.
  const int nloc = l & 15, kg = l >> 4;
  const int group = w8 >> 2, wl = w8 & 3;
  const int r0g = r0 + group * 16;
  const int jid16 = type * (n >> 4) + (j32 << 1) + group;
  const unsigned h = hash_u32((unsigned)jid16 * 2654435761u + 0x9E3779B9u);
  const unsigned bo = h & 8191u;
  const unsigned aa = (((h >> 13) & 4095u) << 1) | 1u;

  bf8 af[4];
  #pragma unroll
  for (int ks = 0; ks < 4; ks++){
    const int kq = ks * 4 + kg;
    af[ks] = *(const bf8*)&A[((group * 16 + nloc) << 7) + ((kq ^ (nloc & 7)) << 3)];
  }

  float M0=-1e30f, M1=-1e30f, M2=-1e30f, M3=-1e30f;
  float S0=0.f, S1=0.f, S2=0.f, S3=0.f;

  for (int tile = wl; tile < 17; tile += 4){
    const int colid = tile * 16 + nloc;
    const int jn = colid - 16;
    const bool isneg = colid >= 16;
    const int g = isneg ? (int)((aa * (unsigned)jn + bo) & 8191u) : (r0g + colid);

    const ushort* __restrict__ xr = x + ((size_t)g << 7);
    f4 acc = {0.f, 0.f, 0.f, 0.f};
    #pragma unroll
    for (int ks = 0; ks < 4; ks++){
      const bf8 bfr = *(const bf8*)(xr + ks * 32 + kg * 8);
      acc = __builtin_amdgcn_mfma_f32_16x16x32_bf16(af[ks], bfr, acc, 0, 0, 0);
    }
    #pragma unroll
    for (int r = 0; r < 4; r++){
      const int row = kg * 4 + r;
      const bool valid = isneg ? (jn < 255 && g != r0g + row) : (colid == row);
      const float v = acc[r] * 10.0f;
      if (!isneg && colid == row) lpos[group * 16 + row] = v;  // tile 0 (wl==0)
      float* Mp; float* Sp;
      if (r == 0){ Mp = &M0; Sp = &S0; } else if (r == 1){ Mp = &M1; Sp = &S1; }
      else if (r == 2){ Mp = &M2; Sp = &S2; } else { Mp = &M3; Sp = &S3; }
      if (valid){
        const float Mn = fmaxf(*Mp, v);
        *Sp = *Sp * __expf(*Mp - Mn) + __expf(v - Mn);
        *Mp = Mn;
      }
    }
  }

  #define MERGE_LANES(MV, SV)                          \
  {                                                    \
    _Pragma("unroll")                                  \
    for (int o = 1; o < 16; o <<= 1){                  \
      const float Mo = __shfl_xor((MV), o);            \
      const float So = __shfl_xor((SV), o);            \
      const float Mn = fmaxf((MV), Mo);                \
      (SV) = (SV) * __expf((MV) - Mn) + So * __expf(Mo - Mn); \
      (MV) = Mn;                                       \
    }                                                  \
  }
  MERGE_LANES(M0, S0) MERGE_LANES(M1, S1) MERGE_LANES(M2, S2) MERGE_LANES(M3, S3)
  #undef MERGE_LANES

  if (nloc == 0){
    part[w8][kg * 4 + 0] = make_float2(M0, S0);
    part[w8][kg * 4 + 1] = make_float2(M1, S1);
    part[w8][kg * 4 + 2] = make_float2(M2, S2);
    part[w8][kg * 4 + 3] = make_float2(M3, S3);
  }
  __syncthreads();

  if ((w8 == 0 || w8 == 4) && l < 16){
    const int row = l;
    float Mm = -1e30f, Ss = 0.f;
    #pragma unroll
    for (int j = 0; j < 4; j++){
      const float2 ps = part[group * 4 + j][row];
      const float Mn = fmaxf(Mm, ps.x);
      Ss = Ss * __expf(Mm - Mn) + ps.y * __expf(ps.x - Mn);
      Mm = Mn;
    }
    float term = Mm + __logf(Ss) - lpos[group * 16 + row];
    #pragma unroll
    for (int o = 8; o >= 1; o >>= 1) term += __shfl_xor(term, o);
    if (l == 0) atomicAdd(out, term / (logf(256.0f) * (float)(2 * n)));
  }
}

extern "C" void kernel_launch(void* const* d_in, const int* in_sizes, int n_in,
                              void* d_out, int out_size, void* d_ws, size_t ws_size,
                              hipStream_t stream) {
  const float* x_a = (const float*)d_in[0];
  const float* x_b = (const float*)d_in[1];
  const float* W_a = (const float*)d_in[2];
  const float* b_a = (const float*)d_in[3];
  const float* W_b = (const float*)d_in[4];
  const float* b_b = (const float*)d_in[5];
  const int*   e_ab = (const int*)d_in[6];   // [2,E]: [0]=src(a), [1]=dst(b)
  const int*   e_ba = (const int*)d_in[7];   // [0]=src(b), [1]=dst(a)
  const int E = in_sizes[6] / 2;
  const int N = in_sizes[0] / D;             // 8192

  char* p = (char*)d_ws;
  ushort* xa16    = (ushort*)p;   p += (size_t)N * D * 2;
  ushort* xb16    = (ushort*)p;   p += (size_t)N * D * 2;
  ushort* ctx0a   = (ushort*)p;   p += (size_t)N * D * 2;
  ushort* ctx0b   = (ushort*)p;   p += (size_t)N * D * 2;
  unsigned* scratch = (unsigned*)p; p += (size_t)2 * BK * CH * CAP * 4;  // 8MB
  unsigned* ccnt  = (unsigned*)p; p += (size_t)2 * BK * CH * 4;          // 256KB

  linear_bin<<<2 * (N / 64) + 2 * CH + 1, 256, 0, stream>>>(
      x_a, x_b, W_a, W_b, b_a, b_b, xa16, xb16, ctx0a, ctx0b,
      e_ba, e_ab, scratch, ccnt, (float*)d_out, E, N);

  loss_fused<<<2 * (N / 32), 512, 0, stream>>>(
      xa16, xb16, ctx0a, ctx0b, scratch, ccnt, (float*)d_out, N);
}

// Round 12
// 43.625 us; speedup vs baseline: 4.1327x; 1.0340x over previous
//
#include <hip/hip_runtime.h>
#include <math.h>

#define D 128
#define DEG 64           // per-node slot capacity (mean degree 32)
#define BK 256           // dst buckets per direction (32 nodes/bucket = 1 loss block)
#define CH 128           // edge chunks per direction (2048 edges/chunk)
#define CAP 32           // slots per (bucket,chunk) cell; mean 8, P(any overflow)~1e-7

typedef __attribute__((ext_vector_type(8))) short bf8;
typedef __attribute__((ext_vector_type(4))) float f4;

__device__ __forceinline__ unsigned hash_u32(unsigned x){
  x ^= x >> 16; x *= 0x7feb352du; x ^= x >> 15; x *= 0x846ca68bu; x ^= x >> 16;
  return x;
}
__device__ __forceinline__ unsigned f2bfbits(float f){
  unsigned u = __float_as_uint(f);
  return (u + 0x7fffu + ((u >> 16) & 1u)) >> 16;   // RNE bf16
}
__device__ __forceinline__ float bflo(unsigned u){ return __uint_as_float(u << 16); }
__device__ __forceinline__ float bfhi(unsigned u){ return __uint_as_float(u & 0xffff0000u); }
__device__ __forceinline__ uint4 pack8(float4 v0, float4 v1){
  uint4 o;
  o.x = f2bfbits(v0.x) | (f2bfbits(v0.y) << 16);
  o.y = f2bfbits(v0.z) | (f2bfbits(v0.w) << 16);
  o.z = f2bfbits(v1.x) | (f2bfbits(v1.y) << 16);
  o.w = f2bfbits(v1.z) | (f2bfbits(v1.w) << 16);
  return o;
}
// XCD-aware type partition (perf heuristic; bijective, correctness-neutral).
__device__ __forceinline__ int xcd_remap(int bid, int jobs_per_type){
  if (jobs_per_type & 3) return bid;
  const int xcd = bid & 7, slot = bid >> 3;
  const int q = jobs_per_type >> 2;
  return (xcd >> 2) * jobs_per_type + (xcd & 3) * q + slot;
}

struct LinS { alignas(16) ushort Ws[64 * 128]; alignas(16) ushort As[4][16 * 128]; }; // 32KB
struct BinS { int hist[BK]; int ex[BK]; int cur[BK]; int wtot[4]; unsigned buf[2048]; }; // ~11.3KB
union SharedU { LinS lin; BinS bin; };

// ---- K1: linear (256 blk) || fixed-slot bin (256 blk) || 1 out-zero block -
// UNCHANGED from r11 (experimental control for this round's loss changes).
__global__ __launch_bounds__(256)
void linear_bin(const float* __restrict__ xa, const float* __restrict__ xb,
                const float* __restrict__ Wa, const float* __restrict__ Wb,
                const float* __restrict__ ba, const float* __restrict__ bb,
                ushort* __restrict__ x16a, ushort* __restrict__ x16b,
                ushort* __restrict__ oa, ushort* __restrict__ ob,
                const int* __restrict__ e_ba, const int* __restrict__ e_ab,
                unsigned* __restrict__ scratch, unsigned* __restrict__ ccnt,
                float* __restrict__ out0, int E, int N){
  const int LB = 2 * (N >> 6);                   // 256 linear blocks (LB%8==0)
  __shared__ SharedU sh;

  if ((int)blockIdx.x < LB){
    // ---------------- ctx0 = bf16(x @ W^T + b) via MFMA ----------------
    const int nb64 = N >> 6;
    const int jid = xcd_remap((int)blockIdx.x, nb64);
    const int type = jid >= nb64;
    const int r0 = (jid - (type ? nb64 : 0)) << 6;
    const float* __restrict__ x = type ? xb : xa;
    const float* __restrict__ W = type ? Wb : Wa;
    const float* __restrict__ bias = type ? bb : ba;
    ushort* __restrict__ x16 = type ? x16b : x16a;
    ushort* __restrict__ out = type ? ob : oa;
    const int t = threadIdx.x, w = t >> 6, l = t & 63;

    #define STAGE_W(H)                                                        \
    {                                                                         \
      _Pragma("unroll")                                                       \
      for (int i = 0; i < 4; i++){                                            \
        const int cid = i * 256 + t;                                          \
        const int col = cid >> 4, kq = cid & 15;                              \
        const int gcol = (H) * 64 + col;                                      \
        const float4 v0 = *(const float4*)(W + (gcol << 7) + (kq << 3));      \
        const float4 v1 = *(const float4*)(W + (gcol << 7) + (kq << 3) + 4);  \
        *(uint4*)&sh.lin.Ws[(col << 7) + ((kq ^ (col & 7)) << 3)] = pack8(v0, v1); \
      }                                                                       \
    }

    #pragma unroll
    for (int i = 0; i < 4; i++){
      const int cid = i * 64 + l;
      const int row = cid >> 4, kq = cid & 15;
      const size_t gr = (size_t)(r0 + w * 16 + row);
      const float4 v0 = *(const float4*)(x + (gr << 7) + (kq << 3));
      const float4 v1 = *(const float4*)(x + (gr << 7) + (kq << 3) + 4);
      const uint4 o = pack8(v0, v1);
      *(uint4*)&sh.lin.As[w][(row << 7) + ((kq ^ (row & 7)) << 3)] = o;
      *(uint4*)(x16 + (gr << 7) + (kq << 3)) = o;  // 1KB/instr coalesced
    }
    STAGE_W(0)
    __syncthreads();

    const int rloc = l & 15, kg = l >> 4;
    bf8 af[4];
    #pragma unroll
    for (int ks = 0; ks < 4; ks++){
      const int kq = ks * 4 + kg;
      af[ks] = *(const bf8*)&sh.lin.As[w][(rloc << 7) + ((kq ^ (rloc & 7)) << 3)];
    }
    #pragma unroll
    for (int h = 0; h < 2; h++){
      if (h == 1){
        __syncthreads();
        STAGE_W(1)
        __syncthreads();
      }
      #pragma unroll
      for (int c2 = 0; c2 < 4; c2++){
        const int ct = h * 4 + c2;
        f4 acc = {0.f, 0.f, 0.f, 0.f};
        const int col = ct * 16 + rloc;
        const int lcol = c2 * 16 + rloc;          // (col&7)==(lcol&7)
        #pragma unroll
        for (int ks = 0; ks < 4; ks++){
          const int kq = ks * 4 + kg;
          const bf8 bfr = *(const bf8*)&sh.lin.Ws[(lcol << 7) + ((kq ^ (lcol & 7)) << 3)];
          acc = __builtin_amdgcn_mfma_f32_16x16x32_bf16(af[ks], bfr, acc, 0, 0, 0);
        }
        const float bv = bias[col];
        #pragma unroll
        for (int r = 0; r < 4; r++){
          const int row = r0 + w * 16 + kg * 4 + r;
          out[((size_t)row << 7) + col] = (ushort)f2bfbits(acc[r] + bv);
        }
      }
    }
    #undef STAGE_W
  } else if ((int)blockIdx.x < LB + 2 * CH){
    // -------- fixed-slot binning: block owns (dir, chunk of 2048) ----------
    const int sbid = (int)blockIdx.x - LB;       // 0..255
    const int d = sbid >> 7, chunk = sbid & 127;
    const int* __restrict__ e = d ? e_ab : e_ba;
    const int t = threadIdx.x;
    #pragma unroll
    for (int i = t; i < BK; i += 256) sh.bin.hist[i] = 0;
    __syncthreads();

    int ds[8], ss[8];
    const int base = chunk * 2048;
    #pragma unroll
    for (int k = 0; k < 8; k++){
      const int i = base + k * 256 + t;
      const bool ok = i < E;
      ds[k] = ok ? e[E + i] : -1;
      ss[k] = ok ? e[i] : 0;
      if (ok) atomicAdd(&sh.bin.hist[ds[k] >> 5], 1);   // LDS atomic, 256 bins
    }
    __syncthreads();
    { // 256-bin inclusive scan: 4 wave-local shfl scans + cross-wave offsets
      int v = sh.bin.hist[t];
      #pragma unroll
      for (int off = 1; off < 64; off <<= 1){
        const int u = __shfl_up(v, off, 64);
        if ((t & 63) >= off) v += u;
      }
      if ((t & 63) == 63) sh.bin.wtot[t >> 6] = v;
      sh.bin.ex[t] = v;
    }
    __syncthreads();
    {
      const int wv = t >> 6;
      int add = 0;
      if (wv > 0) add += sh.bin.wtot[0];
      if (wv > 1) add += sh.bin.wtot[1];
      if (wv > 2) add += sh.bin.wtot[2];
      const int e0 = sh.bin.ex[t] + add - sh.bin.hist[t];  // exclusive start
      sh.bin.ex[t] = e0; sh.bin.cur[t] = e0;
    }
    __syncthreads();
    #pragma unroll
    for (int k = 0; k < 8; k++){
      if (ds[k] >= 0){
        const int p = atomicAdd(&sh.bin.cur[ds[k] >> 5], 1);   // LDS atomic
        sh.bin.buf[p] = (unsigned)ss[k] | ((unsigned)ds[k] << 13);
      }
    }
    __syncthreads();
    int nv = E - base; nv = nv < 0 ? 0 : (nv > 2048 ? 2048 : nv);
    ccnt[((size_t)d * BK + t) * CH + chunk] = (unsigned)min(sh.bin.hist[t], CAP);
    for (int s = t; s < nv; s += 256){
      const unsigned v = sh.bin.buf[s];
      const int bkt = (int)(v >> 18);            // dst>>5
      const int gp = s - sh.bin.ex[bkt];
      if (gp < CAP) scratch[((size_t)(d * BK + bkt) * CH + chunk) * CAP + gp] = v;
    }
  } else {
    if (threadIdx.x == 0) *out0 = 0.0f;
  }
}

// ---- K2: 512 blk x 512 thr x 32 rows. This round: latency/MLP package —
// phase 1 batches 8 gathers into regs before accumulating (same add order),
// phase 2 is a hand-unrolled 2-set software pipeline (load tile k+1 during
// compute of tile k). Numerics bit-identical to r11. ------------------------
__global__ __launch_bounds__(512)
void loss_fused(const ushort* __restrict__ xa, const ushort* __restrict__ xb,
                const ushort* __restrict__ ctx0a, const ushort* __restrict__ ctx0b,
                const unsigned* __restrict__ scratch, const unsigned* __restrict__ ccnt,
                float* __restrict__ out, int n){
  const int nb = n >> 5;                          // 256 jobs per type (32 rows)
  const int jid = xcd_remap((int)blockIdx.x, nb); // XCDs 0-3: type 0, 4-7: type 1
  const int type = jid >= nb;
  const int j32 = jid - (type ? nb : 0);
  const int r0 = j32 << 5;                        // within-type row base
  const ushort* __restrict__ x    = type ? xb : xa;
  const ushort* __restrict__ feat = type ? ctx0a : ctx0b;  // src-side features
  const int t = threadIdx.x, w8 = t >> 6, l = t & 63;
  const int sg = l >> 4, q = l & 15;

  __shared__ alignas(16) ushort A[32 * 128];      // 8KB
  __shared__ float lpos[32];
  __shared__ float2 part[8][16];
  __shared__ int list[32 * DEG];                  // 8KB
  __shared__ int lcnt[32];
  __shared__ unsigned cc[CH];

  if (t < 32) lcnt[t] = 0;
  const size_t cellbase = (size_t)(type * BK + j32) * CH;  // bucket == j32
  if (t < CH) cc[t] = ccnt[cellbase + t];
  __syncthreads();

  { // phase 0: vec4 scan of OWN bucket only (1x amp, 16KB contiguous)
    for (int i4 = t * 4; i4 < CH * CAP; i4 += 512 * 4){    // 2 iters/thread
      const uint4 v4 = *(const uint4*)(scratch + cellbase * CAP + i4);
      const int cell = i4 >> 5;
      const int cn = (int)cc[cell];
      const int s0 = i4 & 31;
      #pragma unroll
      for (int j = 0; j < 4; j++){
        if (s0 + j < cn){
          const unsigned v = (&v4.x)[j];
          const int dl = (int)((v >> 13) & 8191u) - r0;    // in [0,32) by construction
          const int p = atomicAdd(&lcnt[dl], 1);
          if (p < DEG) list[dl * DEG + p] = (int)(v & 8191u);
        }
      }
    }
  }
  __syncthreads();

  { // phase 1: gather-mean, row = w8*4+sg; 8 loads batched into regs (MLP)
    const int row = w8 * 4 + sg;
    const int c = min(lcnt[row], DEG);
    const int lb2 = row * DEG;
    int sl0 = list[lb2 + q];
    int sl1 = list[lb2 + 16 + q];
    int sl2 = list[lb2 + 32 + q];
    int sl3 = list[lb2 + 48 + q];

    float a0=0.f,a1=0.f,a2=0.f,a3=0.f,a4=0.f,a5=0.f,a6=0.f,a7=0.f;
    const int lbase = l & 48;
    #define GMEAN_HALF(SL, J, HB)                                              \
    {                                                                          \
      uint4 vv[8]; float wt[8];                                                \
      _Pragma("unroll")                                                        \
      for (int j = 0; j < 8; j++){                                             \
        const int i = (HB) * 8 + j;                                            \
        const int raw = __shfl((SL), lbase | i, 64);                           \
        const bool ok = (J)*16 + i < c;                                        \
        const int src = ok ? raw : 0;                                          \
        wt[j] = ok ? 1.0f : 0.0f;                                              \
        vv[j] = *(const uint4*)(feat + ((size_t)src << 7) + (q << 3));         \
      }                                                                        \
      _Pragma("unroll")                                                        \
      for (int j = 0; j < 8; j++){                                             \
        a0 += wt[j]*bflo(vv[j].x); a1 += wt[j]*bfhi(vv[j].x);                  \
        a2 += wt[j]*bflo(vv[j].y); a3 += wt[j]*bfhi(vv[j].y);                  \
        a4 += wt[j]*bflo(vv[j].z); a5 += wt[j]*bfhi(vv[j].z);                  \
        a6 += wt[j]*bflo(vv[j].w); a7 += wt[j]*bfhi(vv[j].w);                  \
      }                                                                        \
    }
    if (c >  0){ GMEAN_HALF(sl0, 0, 0) GMEAN_HALF(sl0, 0, 1) }
    if (c > 16){ GMEAN_HALF(sl1, 1, 0) GMEAN_HALF(sl1, 1, 1) }
    if (c > 32){ GMEAN_HALF(sl2, 2, 0) GMEAN_HALF(sl2, 2, 1) }
    if (c > 48){ GMEAN_HALF(sl3, 3, 0) GMEAN_HALF(sl3, 3, 1) }
    #undef GMEAN_HALF

    const float inv = 1.0f / (float)(c > 1 ? c : 1);
    uint4 o;
    o.x = f2bfbits(a0*inv) | (f2bfbits(a1*inv) << 16);
    o.y = f2bfbits(a2*inv) | (f2bfbits(a3*inv) << 16);
    o.z = f2bfbits(a4*inv) | (f2bfbits(a5*inv) << 16);
    o.w = f2bfbits(a6*inv) | (f2bfbits(a7*inv) << 16);
    *(uint4*)&A[(row << 7) + ((q ^ (row & 7)) << 3)] = o;
  }
  __syncthreads();

  // phase 2: two independent 16-row groups; group g on waves 4g..4g+3.
  // Hand-unrolled 2-set pipeline over this wave's tiles {wl, wl+4, wl+8,
  // wl+12, [16 if wl==0]} — LSE update order identical to the r11 loop.
  const int nloc = l & 15, kg = l >> 4;
  const int group = w8 >> 2, wl = w8 & 3;
  const int r0g = r0 + group * 16;
  const int jid16 = type * (n >> 4) + (j32 << 1) + group;
  const unsigned h = hash_u32((unsigned)jid16 * 2654435761u + 0x9E3779B9u);
  const unsigned bo = h & 8191u;
  const unsigned aa = (((h >> 13) & 4095u) << 1) | 1u;

  bf8 af[4];
  #pragma unroll
  for (int ks = 0; ks < 4; ks++){
    const int kq = ks * 4 + kg;
    af[ks] = *(const bf8*)&A[((group * 16 + nloc) << 7) + ((kq ^ (nloc & 7)) << 3)];
  }

  float M0=-1e30f, M1=-1e30f, M2=-1e30f, M3=-1e30f;
  float S0=0.f, S1=0.f, S2=0.f, S3=0.f;

  int colidA, gA; bool negA; bf8 b0A, b1A, b2A, b3A;
  int colidB, gB; bool negB; bf8 b0B, b1B, b2B, b3B;

  #define LOADSET(S, TILE)                                                     \
  {                                                                            \
    colid##S = (TILE) * 16 + nloc;                                             \
    neg##S = colid##S >= 16;                                                   \
    const int jn_ = colid##S - 16;                                             \
    g##S = neg##S ? (int)((aa * (unsigned)jn_ + bo) & 8191u) : (r0g + colid##S); \
    const ushort* __restrict__ xr_ = x + ((size_t)g##S << 7) + kg * 8;         \
    b0##S = *(const bf8*)(xr_);                                                \
    b1##S = *(const bf8*)(xr_ + 32);                                           \
    b2##S = *(const bf8*)(xr_ + 64);                                           \
    b3##S = *(const bf8*)(xr_ + 96);                                           \
  }

  #define COMPUTESET(S)                                                        \
  {                                                                            \
    f4 acc = {0.f, 0.f, 0.f, 0.f};                                             \
    acc = __builtin_amdgcn_mfma_f32_16x16x32_bf16(af[0], b0##S, acc, 0, 0, 0); \
    acc = __builtin_amdgcn_mfma_f32_16x16x32_bf16(af[1], b1##S, acc, 0, 0, 0); \
    acc = __builtin_amdgcn_mfma_f32_16x16x32_bf16(af[2], b2##S, acc, 0, 0, 0); \
    acc = __builtin_amdgcn_mfma_f32_16x16x32_bf16(af[3], b3##S, acc, 0, 0, 0); \
    const int jn_ = colid##S - 16;                                             \
    _Pragma("unroll")                                                          \
    for (int r = 0; r < 4; r++){                                               \
      const int row_ = kg * 4 + r;                                             \
      const bool valid = neg##S ? (jn_ < 255 && g##S != r0g + row_)            \
                                : (colid##S == row_);                          \
      const float v = acc[r] * 10.0f;                                          \
      if (!neg##S && colid##S == row_) lpos[group * 16 + row_] = v;            \
      float* Mp; float* Sp;                                                    \
      if (r == 0){ Mp = &M0; Sp = &S0; } else if (r == 1){ Mp = &M1; Sp = &S1; } \
      else if (r == 2){ Mp = &M2; Sp = &S2; } else { Mp = &M3; Sp = &S3; }     \
      if (valid){                                                              \
        const float Mn = fmaxf(*Mp, v);                                        \
        *Sp = *Sp * __expf(*Mp - Mn) + __expf(v - Mn);                         \
        *Mp = Mn;                                                              \
      }                                                                        \
    }                                                                          \
  }

  LOADSET(A, wl)
  LOADSET(B, wl + 4)
  COMPUTESET(A)                  // tile wl
  LOADSET(A, wl + 8)
  COMPUTESET(B)                  // tile wl+4
  LOADSET(B, wl + 12)
  COMPUTESET(A)                  // tile wl+8
  if (wl == 0){ LOADSET(A, 16) }
  COMPUTESET(B)                  // tile wl+12
  if (wl == 0){ COMPUTESET(A) }  // tile 16 (negatives 240..254)
  #undef LOADSET
  #undef COMPUTESET

  #define MERGE_LANES(MV, SV)                          \
  {                                                    \
    _Pragma("unroll")                                  \
    for (int o = 1; o < 16; o <<= 1){                  \
      const float Mo = __shfl_xor((MV), o);            \
      const float So = __shfl_xor((SV), o);            \
      const float Mn = fmaxf((MV), Mo);                \
      (SV) = (SV) * __expf((MV) - Mn) + So * __expf(Mo - Mn); \
      (MV) = Mn;                                       \
    }                                                  \
  }
  MERGE_LANES(M0, S0) MERGE_LANES(M1, S1) MERGE_LANES(M2, S2) MERGE_LANES(M3, S3)
  #undef MERGE_LANES

  if (nloc == 0){
    part[w8][kg * 4 + 0] = make_float2(M0, S0);
    part[w8][kg * 4 + 1] = make_float2(M1, S1);
    part[w8][kg * 4 + 2] = make_float2(M2, S2);
    part[w8][kg * 4 + 3] = make_float2(M3, S3);
  }
  __syncthreads();

  if ((w8 == 0 || w8 == 4) && l < 16){
    const int row = l;
    float Mm = -1e30f, Ss = 0.f;
    #pragma unroll
    for (int j = 0; j < 4; j++){
      const float2 ps = part[group * 4 + j][row];
      const float Mn = fmaxf(Mm, ps.x);
      Ss = Ss * __expf(Mm - Mn) + ps.y * __expf(ps.x - Mn);
      Mm = Mn;
    }
    float term = Mm + __logf(Ss) - lpos[group * 16 + row];
    #pragma unroll
    for (int o = 8; o >= 1; o >>= 1) term += __shfl_xor(term, o);
    if (l == 0) atomicAdd(out, term / (logf(256.0f) * (float)(2 * n)));
  }
}

extern "C" void kernel_launch(void* const* d_in, const int* in_sizes, int n_in,
                              void* d_out, int out_size, void* d_ws, size_t ws_size,
                              hipStream_t stream) {
  const float* x_a = (const float*)d_in[0];
  const float* x_b = (const float*)d_in[1];
  const float* W_a = (const float*)d_in[2];
  const float* b_a = (const float*)d_in[3];
  const float* W_b = (const float*)d_in[4];
  const float* b_b = (const float*)d_in[5];
  const int*   e_ab = (const int*)d_in[6];   // [2,E]: [0]=src(a), [1]=dst(b)
  const int*   e_ba = (const int*)d_in[7];   // [0]=src(b), [1]=dst(a)
  const int E = in_sizes[6] / 2;
  const int N = in_sizes[0] / D;             // 8192

  char* p = (char*)d_ws;
  ushort* xa16    = (ushort*)p;   p += (size_t)N * D * 2;
  ushort* xb16    = (ushort*)p;   p += (size_t)N * D * 2;
  ushort* ctx0a   = (ushort*)p;   p += (size_t)N * D * 2;
  ushort* ctx0b   = (ushort*)p;   p += (size_t)N * D * 2;
  unsigned* scratch = (unsigned*)p; p += (size_t)2 * BK * CH * CAP * 4;  // 8MB
  unsigned* ccnt  = (unsigned*)p; p += (size_t)2 * BK * CH * 4;          // 256KB

  linear_bin<<<2 * (N / 64) + 2 * CH + 1, 256, 0, stream>>>(
      x_a, x_b, W_a, W_b, b_a, b_b, xa16, xb16, ctx0a, ctx0b,
      e_ba, e_ab, scratch, ccnt, (float*)d_out, E, N);

  loss_fused<<<2 * (N / 32), 512, 0, stream>>>(
      xa16, xb16, ctx0a, ctx0b, scratch, ccnt, (float*)d_out, N);
}

// Round 13
// 42.675 us; speedup vs baseline: 4.2247x; 1.0223x over previous
//
#include <hip/hip_runtime.h>
#include <math.h>

#define D 128
#define DEG 64           // per-node slot capacity (mean degree 32)
#define BK 512           // dst buckets per direction (16 nodes/bucket = 1 loss block)
#define CH 128           // edge chunks per direction (2048 edges/chunk)
#define CAP 24           // slots per (bucket,chunk) cell; mean 4, P(any overflow)~1e-10

typedef __attribute__((ext_vector_type(8))) short bf8;
typedef __attribute__((ext_vector_type(4))) float f4;

__device__ __forceinline__ unsigned hash_u32(unsigned x){
  x ^= x >> 16; x *= 0x7feb352du; x ^= x >> 15; x *= 0x846ca68bu; x ^= x >> 16;
  return x;
}
__device__ __forceinline__ unsigned f2bfbits(float f){
  unsigned u = __float_as_uint(f);
  return (u + 0x7fffu + ((u >> 16) & 1u)) >> 16;   // RNE bf16
}
__device__ __forceinline__ float bflo(unsigned u){ return __uint_as_float(u << 16); }
__device__ __forceinline__ float bfhi(unsigned u){ return __uint_as_float(u & 0xffff0000u); }
__device__ __forceinline__ uint4 pack8(float4 v0, float4 v1){
  uint4 o;
  o.x = f2bfbits(v0.x) | (f2bfbits(v0.y) << 16);
  o.y = f2bfbits(v0.z) | (f2bfbits(v0.w) << 16);
  o.z = f2bfbits(v1.x) | (f2bfbits(v1.y) << 16);
  o.w = f2bfbits(v1.z) | (f2bfbits(v1.w) << 16);
  return o;
}
// XCD-aware type partition (perf heuristic; bijective, correctness-neutral).
__device__ __forceinline__ int xcd_remap(int bid, int jobs_per_type){
  if (jobs_per_type & 3) return bid;
  const int xcd = bid & 7, slot = bid >> 3;
  const int q = jobs_per_type >> 2;
  return (xcd >> 2) * jobs_per_type + (xcd & 3) * q + slot;
}

struct LinS { alignas(16) ushort Ws[64 * 128]; alignas(16) ushort As[4][16 * 128]; }; // 32KB
struct BinS { int hist[BK]; int ex[BK]; int cur[BK]; int wtot[4]; unsigned buf[2048]; }; // ~14.3KB
union SharedU { LinS lin; BinS bin; };

// ---- K1: linear (256 blk) || fixed-slot bin (256 blk) || 1 out-zero block -
__global__ __launch_bounds__(256)
void linear_bin(const float* __restrict__ xa, const float* __restrict__ xb,
                const float* __restrict__ Wa, const float* __restrict__ Wb,
                const float* __restrict__ ba, const float* __restrict__ bb,
                ushort* __restrict__ x16a, ushort* __restrict__ x16b,
                ushort* __restrict__ oa, ushort* __restrict__ ob,
                const int* __restrict__ e_ba, const int* __restrict__ e_ab,
                unsigned* __restrict__ scratch, unsigned* __restrict__ ccnt,
                float* __restrict__ out0, int E, int N){
  const int LB = 2 * (N >> 6);                   // 256 linear blocks (LB%8==0)
  __shared__ SharedU sh;

  if ((int)blockIdx.x < LB){
    // ---------------- ctx0 = bf16(x @ W^T + b) via MFMA (unchanged) -------
    const int nb64 = N >> 6;
    const int jid = xcd_remap((int)blockIdx.x, nb64);
    const int type = jid >= nb64;
    const int r0 = (jid - (type ? nb64 : 0)) << 6;
    const float* __restrict__ x = type ? xb : xa;
    const float* __restrict__ W = type ? Wb : Wa;
    const float* __restrict__ bias = type ? bb : ba;
    ushort* __restrict__ x16 = type ? x16b : x16a;
    ushort* __restrict__ out = type ? ob : oa;
    const int t = threadIdx.x, w = t >> 6, l = t & 63;

    #define STAGE_W(H)                                                        \
    {                                                                         \
      _Pragma("unroll")                                                       \
      for (int i = 0; i < 4; i++){                                            \
        const int cid = i * 256 + t;                                          \
        const int col = cid >> 4, kq = cid & 15;                              \
        const int gcol = (H) * 64 + col;                                      \
        const float4 v0 = *(const float4*)(W + (gcol << 7) + (kq << 3));      \
        const float4 v1 = *(const float4*)(W + (gcol << 7) + (kq << 3) + 4);  \
        *(uint4*)&sh.lin.Ws[(col << 7) + ((kq ^ (col & 7)) << 3)] = pack8(v0, v1); \
      }                                                                       \
    }

    #pragma unroll
    for (int i = 0; i < 4; i++){
      const int cid = i * 64 + l;
      const int row = cid >> 4, kq = cid & 15;
      const size_t gr = (size_t)(r0 + w * 16 + row);
      const float4 v0 = *(const float4*)(x + (gr << 7) + (kq << 3));
      const float4 v1 = *(const float4*)(x + (gr << 7) + (kq << 3) + 4);
      const uint4 o = pack8(v0, v1);
      *(uint4*)&sh.lin.As[w][(row << 7) + ((kq ^ (row & 7)) << 3)] = o;
      *(uint4*)(x16 + (gr << 7) + (kq << 3)) = o;  // 1KB/instr coalesced
    }
    STAGE_W(0)
    __syncthreads();

    const int rloc = l & 15, kg = l >> 4;
    bf8 af[4];
    #pragma unroll
    for (int ks = 0; ks < 4; ks++){
      const int kq = ks * 4 + kg;
      af[ks] = *(const bf8*)&sh.lin.As[w][(rloc << 7) + ((kq ^ (rloc & 7)) << 3)];
    }
    #pragma unroll
    for (int h = 0; h < 2; h++){
      if (h == 1){
        __syncthreads();
        STAGE_W(1)
        __syncthreads();
      }
      #pragma unroll
      for (int c2 = 0; c2 < 4; c2++){
        const int ct = h * 4 + c2;
        f4 acc = {0.f, 0.f, 0.f, 0.f};
        const int col = ct * 16 + rloc;
        const int lcol = c2 * 16 + rloc;          // (col&7)==(lcol&7)
        #pragma unroll
        for (int ks = 0; ks < 4; ks++){
          const int kq = ks * 4 + kg;
          const bf8 bfr = *(const bf8*)&sh.lin.Ws[(lcol << 7) + ((kq ^ (lcol & 7)) << 3)];
          acc = __builtin_amdgcn_mfma_f32_16x16x32_bf16(af[ks], bfr, acc, 0, 0, 0);
        }
        const float bv = bias[col];
        #pragma unroll
        for (int r = 0; r < 4; r++){
          const int row = r0 + w * 16 + kg * 4 + r;
          out[((size_t)row << 7) + col] = (ushort)f2bfbits(acc[r] + bv);
        }
      }
    }
    #undef STAGE_W
  } else if ((int)blockIdx.x < LB + 2 * CH){
    // -------- fixed-slot binning: block owns (dir, chunk of 2048) ----------
    const int sbid = (int)blockIdx.x - LB;       // 0..255
    const int d = sbid >> 7, chunk = sbid & 127;
    const int* __restrict__ e = d ? e_ab : e_ba;
    const int t = threadIdx.x;
    sh.bin.hist[t] = 0; sh.bin.hist[t + 256] = 0;
    __syncthreads();

    int ds[8], ss[8];
    const int base = chunk * 2048;
    #pragma unroll
    for (int k = 0; k < 8; k++){
      const int i = base + k * 256 + t;
      const bool ok = i < E;
      ds[k] = ok ? e[E + i] : -1;
      ss[k] = ok ? e[i] : 0;
      if (ok) atomicAdd(&sh.bin.hist[ds[k] >> 4], 1);   // LDS atomic, 512 bins
    }
    __syncthreads();
    // 512-bin scan: pair-per-thread, wave shfl scans + cross-wave offsets
    const int h0 = sh.bin.hist[2 * t], h1 = sh.bin.hist[2 * t + 1];
    const int pv = h0 + h1;
    {
      int v = pv;
      #pragma unroll
      for (int off = 1; off < 64; off <<= 1){
        const int u = __shfl_up(v, off, 64);
        if ((t & 63) >= off) v += u;
      }
      if ((t & 63) == 63) sh.bin.wtot[t >> 6] = v;
      sh.bin.ex[2 * t] = v;                       // temp: inclusive pair scan
    }
    __syncthreads();
    {
      const int wv = t >> 6;
      int add = 0;
      if (wv > 0) add += sh.bin.wtot[0];
      if (wv > 1) add += sh.bin.wtot[1];
      if (wv > 2) add += sh.bin.wtot[2];
      const int pex = sh.bin.ex[2 * t] + add - pv;   // exclusive start of pair
      sh.bin.ex[2 * t] = pex;      sh.bin.ex[2 * t + 1] = pex + h0;
      sh.bin.cur[2 * t] = pex;     sh.bin.cur[2 * t + 1] = pex + h0;
    }
    __syncthreads();
    #pragma unroll
    for (int k = 0; k < 8; k++){
      if (ds[k] >= 0){
        const int p = atomicAdd(&sh.bin.cur[ds[k] >> 4], 1);   // LDS atomic
        sh.bin.buf[p] = (unsigned)ss[k] | ((unsigned)ds[k] << 13);
      }
    }
    __syncthreads();
    int nv = E - base; nv = nv < 0 ? 0 : (nv > 2048 ? 2048 : nv);
    ccnt[((size_t)d * BK + 2 * t) * CH + chunk]     = (unsigned)min(h0, CAP);
    ccnt[((size_t)d * BK + 2 * t + 1) * CH + chunk] = (unsigned)min(h1, CAP);
    for (int s = t; s < nv; s += 256){
      const unsigned v = sh.bin.buf[s];
      const int bkt = (int)(v >> 17);            // dst>>4
      const int gp = s - sh.bin.ex[bkt];
      if (gp < CAP) scratch[((size_t)(d * BK + bkt) * CH + chunk) * CAP + gp] = v;
    }
  } else {
    if (threadIdx.x == 0) *out0 = 0.0f;
  }
}

// ---- K2: 1024 blk x 256 thr x 16 rows. Smaller barrier domain, ~4 blocks/CU,
// finer tail. Bucket == block (1x-amp 12KB scan). Job math bit-identical to
// r12/r9 (hash keyed on type*512+j16). MLP phase-1 batching + 2-set phase-2
// pipeline carried over unchanged. -----------------------------------------
__global__ __launch_bounds__(256)
void loss_fused(const ushort* __restrict__ xa, const ushort* __restrict__ xb,
                const ushort* __restrict__ ctx0a, const ushort* __restrict__ ctx0b,
                const unsigned* __restrict__ scratch, const unsigned* __restrict__ ccnt,
                float* __restrict__ out, int n){
  const int nb = n >> 4;                          // 512 jobs per type (16 rows)
  const int jid = xcd_remap((int)blockIdx.x, nb); // XCDs 0-3: type 0, 4-7: type 1
  const int type = jid >= nb;
  const int j16 = jid - (type ? nb : 0);
  const int r0 = j16 << 4;                        // within-type row base
  const ushort* __restrict__ x    = type ? xb : xa;
  const ushort* __restrict__ feat = type ? ctx0a : ctx0b;  // src-side features
  const int t = threadIdx.x, w = t >> 6, l = t & 63;
  const int sg = l >> 4, q = l & 15;

  __shared__ alignas(16) ushort A[16 * 128];      // 4KB
  __shared__ float lpos[16];
  __shared__ float2 part[4][16];
  __shared__ int list[16 * DEG];                  // 4KB
  __shared__ int lcnt[16];
  __shared__ unsigned cc[CH];

  if (t < 16) lcnt[t] = 0;
  const size_t cellbase = (size_t)(type * BK + j16) * CH;  // bucket == j16
  if (t < CH) cc[t] = ccnt[cellbase + t];
  __syncthreads();

  { // phase 0: vec4 scan of OWN bucket only (1x amp, 12KB contiguous)
    for (int i4 = t * 4; i4 < CH * CAP; i4 += 256 * 4){    // 3 iters/thread
      const uint4 v4 = *(const uint4*)(scratch + cellbase * CAP + i4);
      const int cell = i4 / CAP;
      const int s0 = i4 - cell * CAP;
      const int cn = (int)cc[cell];
      #pragma unroll
      for (int j = 0; j < 4; j++){
        if (s0 + j < cn){
          const unsigned v = (&v4.x)[j];
          const int dl = (int)((v >> 13) & 8191u) - r0;    // in [0,16) by construction
          const int p = atomicAdd(&lcnt[dl], 1);
          if (p < DEG) list[dl * DEG + p] = (int)(v & 8191u);
        }
      }
    }
  }
  __syncthreads();

  { // phase 1: gather-mean, row = w*4+sg; 8 loads batched into regs (MLP)
    const int row = w * 4 + sg;
    const int c = min(lcnt[row], DEG);
    const int lb2 = row * DEG;
    int sl0 = list[lb2 + q];
    int sl1 = list[lb2 + 16 + q];
    int sl2 = list[lb2 + 32 + q];
    int sl3 = list[lb2 + 48 + q];

    float a0=0.f,a1=0.f,a2=0.f,a3=0.f,a4=0.f,a5=0.f,a6=0.f,a7=0.f;
    const int lbase = l & 48;
    #define GMEAN_HALF(SL, J, HB)                                              \
    {                                                                          \
      uint4 vv[8]; float wt[8];                                                \
      _Pragma("unroll")                                                        \
      for (int j = 0; j < 8; j++){                                             \
        const int i = (HB) * 8 + j;                                            \
        const int raw = __shfl((SL), lbase | i, 64);                           \
        const bool ok = (J)*16 + i < c;                                        \
        const int src = ok ? raw : 0;                                          \
        wt[j] = ok ? 1.0f : 0.0f;                                              \
        vv[j] = *(const uint4*)(feat + ((size_t)src << 7) + (q << 3));         \
      }                                                                        \
      _Pragma("unroll")                                                        \
      for (int j = 0; j < 8; j++){                                             \
        a0 += wt[j]*bflo(vv[j].x); a1 += wt[j]*bfhi(vv[j].x);                  \
        a2 += wt[j]*bflo(vv[j].y); a3 += wt[j]*bfhi(vv[j].y);                  \
        a4 += wt[j]*bflo(vv[j].z); a5 += wt[j]*bfhi(vv[j].z);                  \
        a6 += wt[j]*bflo(vv[j].w); a7 += wt[j]*bfhi(vv[j].w);                  \
      }                                                                        \
    }
    if (c >  0){ GMEAN_HALF(sl0, 0, 0) GMEAN_HALF(sl0, 0, 1) }
    if (c > 16){ GMEAN_HALF(sl1, 1, 0) GMEAN_HALF(sl1, 1, 1) }
    if (c > 32){ GMEAN_HALF(sl2, 2, 0) GMEAN_HALF(sl2, 2, 1) }
    if (c > 48){ GMEAN_HALF(sl3, 3, 0) GMEAN_HALF(sl3, 3, 1) }
    #undef GMEAN_HALF

    const float inv = 1.0f / (float)(c > 1 ? c : 1);
    uint4 o;
    o.x = f2bfbits(a0*inv) | (f2bfbits(a1*inv) << 16);
    o.y = f2bfbits(a2*inv) | (f2bfbits(a3*inv) << 16);
    o.z = f2bfbits(a4*inv) | (f2bfbits(a5*inv) << 16);
    o.w = f2bfbits(a6*inv) | (f2bfbits(a7*inv) << 16);
    *(uint4*)&A[(row << 7) + ((q ^ (row & 7)) << 3)] = o;
  }
  __syncthreads();

  // phase 2: 2-set software pipeline over this wave's tiles {w, w+4, w+8,
  // w+12, [16 if w==0]} — LSE order identical to r12/r9.
  const int nloc = l & 15, kg = l >> 4;
  const unsigned h = hash_u32((unsigned)jid * 2654435761u + 0x9E3779B9u);
  const unsigned bo = h & 8191u;
  const unsigned aa = (((h >> 13) & 4095u) << 1) | 1u;

  bf8 af[4];
  #pragma unroll
  for (int ks = 0; ks < 4; ks++){
    const int kq = ks * 4 + kg;
    af[ks] = *(const bf8*)&A[(nloc << 7) + ((kq ^ (nloc & 7)) << 3)];
  }

  float M0=-1e30f, M1=-1e30f, M2=-1e30f, M3=-1e30f;
  float S0=0.f, S1=0.f, S2=0.f, S3=0.f;

  int colidA, gA; bool negA; bf8 b0A, b1A, b2A, b3A;
  int colidB, gB; bool negB; bf8 b0B, b1B, b2B, b3B;

  #define LOADSET(S, TILE)                                                     \
  {                                                                            \
    colid##S = (TILE) * 16 + nloc;                                             \
    neg##S = colid##S >= 16;                                                   \
    const int jn_ = colid##S - 16;                                             \
    g##S = neg##S ? (int)((aa * (unsigned)jn_ + bo) & 8191u) : (r0 + colid##S); \
    const ushort* __restrict__ xr_ = x + ((size_t)g##S << 7) + kg * 8;         \
    b0##S = *(const bf8*)(xr_);                                                \
    b1##S = *(const bf8*)(xr_ + 32);                                           \
    b2##S = *(const bf8*)(xr_ + 64);                                           \
    b3##S = *(const bf8*)(xr_ + 96);                                           \
  }

  #define COMPUTESET(S)                                                        \
  {                                                                            \
    f4 acc = {0.f, 0.f, 0.f, 0.f};                                             \
    acc = __builtin_amdgcn_mfma_f32_16x16x32_bf16(af[0], b0##S, acc, 0, 0, 0); \
    acc = __builtin_amdgcn_mfma_f32_16x16x32_bf16(af[1], b1##S, acc, 0, 0, 0); \
    acc = __builtin_amdgcn_mfma_f32_16x16x32_bf16(af[2], b2##S, acc, 0, 0, 0); \
    acc = __builtin_amdgcn_mfma_f32_16x16x32_bf16(af[3], b3##S, acc, 0, 0, 0); \
    const int jn_ = colid##S - 16;                                             \
    _Pragma("unroll")                                                          \
    for (int r = 0; r < 4; r++){                                               \
      const int row_ = kg * 4 + r;                                             \
      const bool valid = neg##S ? (jn_ < 255 && g##S != r0 + row_)             \
                                : (colid##S == row_);                          \
      const float v = acc[r] * 10.0f;                                          \
      if (!neg##S && colid##S == row_) lpos[row_] = v;                         \
      float* Mp; float* Sp;                                                    \
      if (r == 0){ Mp = &M0; Sp = &S0; } else if (r == 1){ Mp = &M1; Sp = &S1; } \
      else if (r == 2){ Mp = &M2; Sp = &S2; } else { Mp = &M3; Sp = &S3; }     \
      if (valid){                                                              \
        const float Mn = fmaxf(*Mp, v);                                        \
        *Sp = *Sp * __expf(*Mp - Mn) + __expf(v - Mn);                         \
        *Mp = Mn;                                                              \
      }                                                                        \
    }                                                                          \
  }

  LOADSET(A, w)
  LOADSET(B, w + 4)
  COMPUTESET(A)                  // tile w
  LOADSET(A, w + 8)
  COMPUTESET(B)                  // tile w+4
  LOADSET(B, w + 12)
  COMPUTESET(A)                  // tile w+8
  if (w == 0){ LOADSET(A, 16) }
  COMPUTESET(B)                  // tile w+12
  if (w == 0){ COMPUTESET(A) }   // tile 16 (negatives 240..254)
  #undef LOADSET
  #undef COMPUTESET

  #define MERGE_LANES(MV, SV)                          \
  {                                                    \
    _Pragma("unroll")                                  \
    for (int o = 1; o < 16; o <<= 1){                  \
      const float Mo = __shfl_xor((MV), o);            \
      const float So = __shfl_xor((SV), o);            \
      const float Mn = fmaxf((MV), Mo);                \
      (SV) = (SV) * __expf((MV) - Mn) + So * __expf(Mo - Mn); \
      (MV) = Mn;                                       \
    }                                                  \
  }
  MERGE_LANES(M0, S0) MERGE_LANES(M1, S1) MERGE_LANES(M2, S2) MERGE_LANES(M3, S3)
  #undef MERGE_LANES

  if (nloc == 0){
    part[w][kg * 4 + 0] = make_float2(M0, S0);
    part[w][kg * 4 + 1] = make_float2(M1, S1);
    part[w][kg * 4 + 2] = make_float2(M2, S2);
    part[w][kg * 4 + 3] = make_float2(M3, S3);
  }
  __syncthreads();

  if (w == 0 && l < 16){
    const int row = l;
    float Mm = -1e30f, Ss = 0.f;
    #pragma unroll
    for (int j = 0; j < 4; j++){
      const float2 ps = part[j][row];
      const float Mn = fmaxf(Mm, ps.x);
      Ss = Ss * __expf(Mm - Mn) + ps.y * __expf(ps.x - Mn);
      Mm = Mn;
    }
    float term = Mm + __logf(Ss) - lpos[row];
    #pragma unroll
    for (int o = 8; o >= 1; o >>= 1) term += __shfl_xor(term, o);
    if (l == 0) atomicAdd(out, term / (logf(256.0f) * (float)(2 * n)));
  }
}

extern "C" void kernel_launch(void* const* d_in, const int* in_sizes, int n_in,
                              void* d_out, int out_size, void* d_ws, size_t ws_size,
                              hipStream_t stream) {
  const float* x_a = (const float*)d_in[0];
  const float* x_b = (const float*)d_in[1];
  const float* W_a = (const float*)d_in[2];
  const float* b_a = (const float*)d_in[3];
  const float* W_b = (const float*)d_in[4];
  const float* b_b = (const float*)d_in[5];
  const int*   e_ab = (const int*)d_in[6];   // [2,E]: [0]=src(a), [1]=dst(b)
  const int*   e_ba = (const int*)d_in[7];   // [0]=src(b), [1]=dst(a)
  const int E = in_sizes[6] / 2;
  const int N = in_sizes[0] / D;             // 8192

  char* p = (char*)d_ws;
  ushort* xa16    = (ushort*)p;   p += (size_t)N * D * 2;
  ushort* xb16    = (ushort*)p;   p += (size_t)N * D * 2;
  ushort* ctx0a   = (ushort*)p;   p += (size_t)N * D * 2;
  ushort* ctx0b   = (ushort*)p;   p += (size_t)N * D * 2;
  unsigned* scratch = (unsigned*)p; p += (size_t)2 * BK * CH * CAP * 4;  // 12.6MB
  unsigned* ccnt  = (unsigned*)p; p += (size_t)2 * BK * CH * 4;          // 512KB

  linear_bin<<<2 * (N / 64) + 2 * CH + 1, 256, 0, stream>>>(
      x_a, x_b, W_a, W_b, b_a, b_b, xa16, xb16, ctx0a, ctx0b,
      e_ba, e_ab, scratch, ccnt, (float*)d_out, E, N);

  loss_fused<<<2 * (N / 16), 256, 0, stream>>>(
      xa16, xb16, ctx0a, ctx0b, scratch, ccnt, (float*)d_out, N);
}